// Round 2
// baseline (5916.464 us; speedup 1.0000x reference)
//
#include <hip/hip_runtime.h>
#include <hip/hip_bf16.h>
#include <math.h>

// ---------------------------------------------------------------------------
// PicanetG: Renet (2x BiLSTM, HID=256) + 1x1 conv(484) + softmax + attention.
// Round 1: correctness build, bf16 intermediates to fit d_ws (~133 MiB needed).
//   B=8, C=512, H=W=64, HID=256. Output [8,512,64,64] fp32.
//
// ws layout (float-offset units):
//   G   @ 0         : [32768][1024] bf16 gate pre-acts (64 MiB)
//                     -- later aliased by Kern [8][512][4096] fp32 (64 MiB)
//   V   @ 16777216  : [512 seq(b,h)][64 t=w][512] bf16 vertical out (32 MiB)
//                     -- later aliased by Pch [8][512][512] fp32 (8 MiB)
//   HF  @ 25165824  : [512 seq(b,w)][64 t=h][512] bf16 horizontal out (32 MiB)
//   Wt  @ 33554432  : 4x transposed Whh [256][1024] fp32 (4 MiB)
//   cw2 @ 34603008  : conv_w zero-padded [512][512] fp32 (1 MiB)
//   cb2 @ 34865152  : conv_b zero-padded [512]
//   total: 34865664 floats = 139,462,656 bytes (~133 MiB)
// ---------------------------------------------------------------------------

typedef __hip_bfloat16 bf16;

__device__ __forceinline__ float toF(float v) { return v; }
__device__ __forceinline__ float toF(bf16 v)  { return __bfloat162float(v); }
__device__ __forceinline__ unsigned short bfbits(float f) {
    bf16 h = __float2bfloat16(f);
    return *reinterpret_cast<unsigned short*>(&h);
}

// ---------------------------------------------------------------------------
// prep: transpose the 4 Whh matrices [1024,256]->[256,1024]; pad conv weights.
// ---------------------------------------------------------------------------
__global__ __launch_bounds__(256)
void prep_kernel(const float* __restrict__ vwf, const float* __restrict__ vwb,
                 const float* __restrict__ hwf, const float* __restrict__ hwb,
                 const float* __restrict__ cw,  const float* __restrict__ cb,
                 float* __restrict__ Wt, float* __restrict__ cw2, float* __restrict__ cb2)
{
    int idx = blockIdx.x * 256 + threadIdx.x;
    if (idx < 1048576) {                       // 4 x 262144
        int mat = idx >> 18, rem = idx & 262143;
        int k = rem >> 10, g = rem & 1023;
        const float* src = (mat == 0) ? vwf : (mat == 1) ? vwb : (mat == 2) ? hwf : hwb;
        Wt[idx] = src[g * 256 + k];
    } else if (idx < 1048576 + 262144) {
        int r = idx - 1048576; int o = r >> 9, k = r & 511;
        cw2[r] = (o < 484) ? cw[o * 512 + k] : 0.f;
    } else if (idx < 1048576 + 262144 + 512) {
        int o = idx - 1048576 - 262144;
        cb2[o] = (o < 484) ? cb[o] : 0.f;
    }
}

// ---------------------------------------------------------------------------
// Generic GEMM:  out[n,g] = sum_k A[n,k] * W[g,k] + bias[g]   (fp32 accum)
// A address: f(n) = (n>>12)*sA + ((n>>6)&63)*s1 + (n&63)*s0, element k at +k*sK.
// AMODE 0: lanes contiguous along n (phase V: x input fp32, sK=4096)
// AMODE 1: lanes contiguous along k (phase H / conv: bf16 input, sK=1)
// OMODE 0: out[n*Ncols + g]  (bf16 gate buffer)
// OMODE 1: out[(n>>12)*2097152 + g*4096 + (n&4095)]  (fp32 kern layout)
// Tile: BM=128 (n) x BN=64 (g) x BK=16, 256 threads, 8x4 per thread.
// ---------------------------------------------------------------------------
template<int AMODE, typename TA, int OMODE, typename TO>
__global__ __launch_bounds__(256)
void gemm_k1(const TA* __restrict__ A, const float* __restrict__ W,
             const float* __restrict__ bias, TO* __restrict__ out,
             int sA, int s1, int s0, int sK, int ldw, int Ncols)
{
    __shared__ float As[16][132];
    __shared__ float Bs[16][68];
    const int tid = threadIdx.x;
    const int g0 = blockIdx.x << 6;
    const int n0 = blockIdx.y << 7;
    const int tm = tid & 15, tn = tid >> 4;
    float acc[8][4];
    #pragma unroll
    for (int i = 0; i < 8; ++i)
        #pragma unroll
        for (int j = 0; j < 4; ++j) acc[i][j] = 0.f;

    for (int k0 = 0; k0 < 512; k0 += 16) {
        if (AMODE == 0) {
            int ln = tid & 127;
            int n  = n0 + ln;
            long fa = (long)(n >> 12) * sA + (long)((n >> 6) & 63) * s1 + (long)(n & 63) * s0;
            int lk = tid >> 7;   // 0..1
            #pragma unroll
            for (int r = 0; r < 8; ++r) {
                int kk = lk + (r << 1);
                As[kk][ln] = toF(A[fa + (long)(k0 + kk) * sK]);
            }
        } else {
            int lk = tid & 15, ln0 = tid >> 4;
            #pragma unroll
            for (int r = 0; r < 8; ++r) {
                int n = n0 + ln0 + (r << 4);
                long fa = (long)(n >> 12) * sA + (long)((n >> 6) & 63) * s1 + (long)(n & 63) * s0;
                As[lk][ln0 + (r << 4)] = toF(A[fa + (long)(k0 + lk) * sK]);
            }
        }
        {
            int lk = tid & 15, lg = tid >> 4;
            #pragma unroll
            for (int r = 0; r < 4; ++r) {
                int g = g0 + lg + (r << 4);
                Bs[lk][lg + (r << 4)] = W[(long)g * ldw + k0 + lk];
            }
        }
        __syncthreads();
        #pragma unroll
        for (int kk = 0; kk < 16; ++kk) {
            float4 a0 = *(const float4*)&As[kk][tm << 2];
            float4 a1 = *(const float4*)&As[kk][(tm << 2) + 64];
            float4 bf = *(const float4*)&Bs[kk][tn << 2];
            float av[8] = {a0.x,a0.y,a0.z,a0.w,a1.x,a1.y,a1.z,a1.w};
            float bv[4] = {bf.x,bf.y,bf.z,bf.w};
            #pragma unroll
            for (int i = 0; i < 8; ++i)
                #pragma unroll
                for (int j = 0; j < 4; ++j)
                    acc[i][j] += av[i] * bv[j];
        }
        __syncthreads();
    }

    float bvals[4];
    #pragma unroll
    for (int j = 0; j < 4; ++j) bvals[j] = bias[g0 + (tn << 2) + j];

    #pragma unroll
    for (int i = 0; i < 8; ++i) {
        int m = n0 + (tm << 2) + (i & 3) + ((i >> 2) << 6);
        if (OMODE == 0) {
            // bf16 gate store: 4 consecutive g -> 8-byte store
            ushort4 u;
            u.x = bfbits(acc[i][0] + bvals[0]);
            u.y = bfbits(acc[i][1] + bvals[1]);
            u.z = bfbits(acc[i][2] + bvals[2]);
            u.w = bfbits(acc[i][3] + bvals[3]);
            *(ushort4*)&out[(long)m * Ncols + g0 + (tn << 2)] = u;
        } else {
            long ob = (long)(m >> 12) * 2097152 + (m & 4095);
            #pragma unroll
            for (int j = 0; j < 4; ++j)
                ((float*)out)[ob + (long)(g0 + (tn << 2) + j) * 4096] = acc[i][j] + bvals[j];
        }
    }
}

// ---------------------------------------------------------------------------
// LSTM recurrence. G: [512 seq][64 t][1024] bf16 gate pre-acts.
// Wt: transposed Whh [256 k][1024 g] fp32. Vout (bf16): h at [(s*64+t)*512 + j].
// One WG = 4 sequences, 256 threads; thread j owns gates {j, j+256, j+512, j+768}.
// h kept in fp32 in LDS; only the exported copy is bf16-rounded.
// ---------------------------------------------------------------------------
__global__ __launch_bounds__(256)
void lstm_recur(const bf16* __restrict__ G, const float* __restrict__ Wt,
                bf16* __restrict__ Vout, int reverse)
{
    __shared__ float hsh[4][256];
    const int j = threadIdx.x;
    const int s0 = blockIdx.x * 4;
    float c[4] = {0.f, 0.f, 0.f, 0.f};
    #pragma unroll
    for (int s = 0; s < 4; ++s) hsh[s][j] = 0.f;
    __syncthreads();

    for (int step = 0; step < 64; ++step) {
        const int t = reverse ? (63 - step) : step;
        float acc[4][4];
        #pragma unroll
        for (int s = 0; s < 4; ++s) {
            const bf16* gb = G + ((long)(s0 + s) * 64 + t) * 1024 + j;
            acc[s][0] = toF(gb[0]);   acc[s][1] = toF(gb[256]);
            acc[s][2] = toF(gb[512]); acc[s][3] = toF(gb[768]);
        }
        #pragma unroll 4
        for (int k = 0; k < 256; ++k) {
            const float* wr = Wt + k * 1024 + j;
            float w0 = wr[0], w1 = wr[256], w2 = wr[512], w3 = wr[768];
            #pragma unroll
            for (int s = 0; s < 4; ++s) {
                float hv = hsh[s][k];
                acc[s][0] += w0 * hv; acc[s][1] += w1 * hv;
                acc[s][2] += w2 * hv; acc[s][3] += w3 * hv;
            }
        }
        __syncthreads();
        #pragma unroll
        for (int s = 0; s < 4; ++s) {
            float ii = 1.f / (1.f + __expf(-acc[s][0]));
            float ff = 1.f / (1.f + __expf(-acc[s][1]));
            float gg = tanhf(acc[s][2]);
            float oo = 1.f / (1.f + __expf(-acc[s][3]));
            c[s] = ff * c[s] + ii * gg;
            float hh = oo * tanhf(c[s]);
            hsh[s][j] = hh;
            Vout[((long)(s0 + s) * 64 + t) * 512 + j] = __float2bfloat16(hh);
        }
        __syncthreads();
    }
}

// ---------------------------------------------------------------------------
// Softmax over o=0..483 of kern [8][512][4096] fp32 (rows 484..511 stay 0).
// One WG = (b, 16 consecutive p). Tile staged in LDS.
// ---------------------------------------------------------------------------
__global__ __launch_bounds__(256)
void softmax484(float* __restrict__ kern)
{
    __shared__ float tile[484][16];
    __shared__ float red[16][17];
    __shared__ float mx[16], inv[16];
    const int b  = blockIdx.x >> 8;
    const int p0 = (blockIdx.x & 255) << 4;
    float* base = kern + (long)b * 2097152 + p0;
    const int pp = threadIdx.x & 15, oo = threadIdx.x >> 4;

    float pm = -3.4e38f;
    #pragma unroll 4
    for (int r = 0; r < 31; ++r) {
        int o = oo + (r << 4);
        if (o < 484) {
            float v = base[(long)o * 4096 + pp];
            tile[o][pp] = v;
            pm = fmaxf(pm, v);
        }
    }
    red[oo][pp] = pm;
    __syncthreads();
    if (oo == 0) {
        float m = red[0][pp];
        #pragma unroll
        for (int q = 1; q < 16; ++q) m = fmaxf(m, red[q][pp]);
        mx[pp] = m;
    }
    __syncthreads();
    float m = mx[pp];
    float ps = 0.f;
    #pragma unroll 4
    for (int r = 0; r < 31; ++r) {
        int o = oo + (r << 4);
        if (o < 484) {
            float e = __expf(tile[o][pp] - m);
            tile[o][pp] = e;
            ps += e;
        }
    }
    red[oo][pp] = ps;
    __syncthreads();
    if (oo == 0) {
        float s = 0.f;
        #pragma unroll
        for (int q = 0; q < 16; ++q) s += red[q][pp];
        inv[pp] = 1.f / s;
    }
    __syncthreads();
    float iv = inv[pp];
    #pragma unroll 4
    for (int r = 0; r < 31; ++r) {
        int o = oo + (r << 4);
        if (o < 484) base[(long)o * 4096 + pp] = tile[o][pp] * iv;
    }
}

// ---------------------------------------------------------------------------
// Gather dilated patch: Pch[b][c][o] = x[b, c, 3*(o/22), 3*(o%22)], 0-pad o>=484.
// ---------------------------------------------------------------------------
__global__ __launch_bounds__(256)
void gather_patch(const float* __restrict__ x, float* __restrict__ Pch)
{
    int idx = blockIdx.x * 256 + threadIdx.x;
    if (idx >= 2097152) return;
    int o = idx & 511, c = (idx >> 9) & 511, b = idx >> 18;
    float v = 0.f;
    if (o < 484) {
        int i = o / 22, jj = o - i * 22;
        v = x[(long)b * 2097152 + (long)c * 4096 + i * 192 + jj * 3];
    }
    Pch[idx] = v;
}

// ---------------------------------------------------------------------------
// Final attention GEMM: out[b*512+c][p] = sum_k Pch[(b*512+c)*512+k] * kern[b][k][p]
// Tile 128x64, K=512 (zero-padded), per-b B matrix. Grid: (64 ptiles, 32 mtiles).
// ---------------------------------------------------------------------------
__global__ __launch_bounds__(256)
void final_gemm(const float* __restrict__ Pch, const float* __restrict__ kern,
                float* __restrict__ out)
{
    __shared__ float As[16][132];
    __shared__ float Bs[16][68];
    const int tid = threadIdx.x;
    const int p0 = blockIdx.x << 6;
    const int n0 = blockIdx.y << 7;
    const int b  = n0 >> 9;
    const float* Bb = kern + (long)b * 2097152;
    const int tm = tid & 15, tn = tid >> 4;
    float acc[8][4];
    #pragma unroll
    for (int i = 0; i < 8; ++i)
        #pragma unroll
        for (int j = 0; j < 4; ++j) acc[i][j] = 0.f;

    for (int k0 = 0; k0 < 512; k0 += 16) {
        {
            int lk = tid & 15, ln0 = tid >> 4;
            #pragma unroll
            for (int r = 0; r < 8; ++r) {
                int n = n0 + ln0 + (r << 4);
                As[lk][ln0 + (r << 4)] = Pch[(long)n * 512 + k0 + lk];
            }
        }
        {
            int lp = tid & 63, lkb = tid >> 6;
            #pragma unroll
            for (int r = 0; r < 4; ++r) {
                int kk = lkb + (r << 2);
                Bs[kk][lp] = Bb[(long)(k0 + kk) * 4096 + p0 + lp];
            }
        }
        __syncthreads();
        #pragma unroll
        for (int kk = 0; kk < 16; ++kk) {
            float4 a0 = *(const float4*)&As[kk][tm << 2];
            float4 a1 = *(const float4*)&As[kk][(tm << 2) + 64];
            float4 bf = *(const float4*)&Bs[kk][tn << 2];
            float av[8] = {a0.x,a0.y,a0.z,a0.w,a1.x,a1.y,a1.z,a1.w};
            float bv[4] = {bf.x,bf.y,bf.z,bf.w};
            #pragma unroll
            for (int i = 0; i < 8; ++i)
                #pragma unroll
                for (int j = 0; j < 4; ++j)
                    acc[i][j] += av[i] * bv[j];
        }
        __syncthreads();
    }
    #pragma unroll
    for (int i = 0; i < 8; ++i) {
        int m = n0 + (tm << 2) + (i & 3) + ((i >> 2) << 6);
        float4 v4 = make_float4(acc[i][0], acc[i][1], acc[i][2], acc[i][3]);
        *(float4*)&out[(long)m * 4096 + p0 + (tn << 2)] = v4;
    }
}

// ---------------------------------------------------------------------------
extern "C" void kernel_launch(void* const* d_in, const int* in_sizes, int n_in,
                              void* d_out, int out_size, void* d_ws, size_t ws_size,
                              hipStream_t stream)
{
    const float* x        = (const float*)d_in[0];
    const float* v_wih_f  = (const float*)d_in[1];
    const float* v_whh_f  = (const float*)d_in[2];
    const float* v_b_f    = (const float*)d_in[3];
    const float* v_wih_b  = (const float*)d_in[4];
    const float* v_whh_b  = (const float*)d_in[5];
    const float* v_b_b    = (const float*)d_in[6];
    const float* h_wih_f  = (const float*)d_in[7];
    const float* h_whh_f  = (const float*)d_in[8];
    const float* h_b_f    = (const float*)d_in[9];
    const float* h_wih_b  = (const float*)d_in[10];
    const float* h_whh_b  = (const float*)d_in[11];
    const float* h_b_b    = (const float*)d_in[12];
    const float* conv_w   = (const float*)d_in[13];
    const float* conv_b   = (const float*)d_in[14];

    // ws budget check: need 139,462,656 bytes. If d_ws is smaller, launch
    // nothing -> clean absmax failure (~0.193) tells us ws_size is the limit
    // (as opposed to the round-0 crash signature).
    const size_t REQ = 34865664UL * 4UL;
    if (ws_size < REQ) return;

    float* base = (float*)d_ws;
    bf16*  G    = (bf16*)d_ws;                       // 64 MiB
    bf16*  V    = (bf16*)(base + 16777216);          // 32 MiB
    bf16*  HF   = (bf16*)(base + 25165824);          // 32 MiB
    float* Wt   = base + 33554432;                   // 4 MiB
    float* cw2  = base + 34603008;                   // 1 MiB
    float* cb2  = base + 34865152;
    float* Kern = (float*)d_ws;                      // aliases G (dead then)
    float* Pch  = base + 16777216;                   // aliases V (dead then)
    float* out  = (float*)d_out;

    prep_kernel<<<5122, 256, 0, stream>>>(v_whh_f, v_whh_b, h_whh_f, h_whh_b,
                                          conv_w, conv_b, Wt, cw2, cb2);

    dim3 gg(16, 256);   // 1024/64 gtiles x 32768/128 mtiles
    // ---- vertical BiLSTM (seq along w, input x fp32) ----
    gemm_k1<0, float, 0, bf16><<<gg, 256, 0, stream>>>(x, v_wih_f, v_b_f, G, 2097152, 64, 1, 4096, 512, 1024);
    lstm_recur<<<128, 256, 0, stream>>>(G, Wt, V, 0);
    gemm_k1<0, float, 0, bf16><<<gg, 256, 0, stream>>>(x, v_wih_b, v_b_b, G, 2097152, 64, 1, 4096, 512, 1024);
    lstm_recur<<<128, 256, 0, stream>>>(G, Wt + 262144, V + 256, 1);

    // ---- horizontal BiLSTM (seq along h, input V bf16) ----
    gemm_k1<1, bf16, 0, bf16><<<gg, 256, 0, stream>>>(V, h_wih_f, h_b_f, G, 2097152, 512, 32768, 1, 512, 1024);
    lstm_recur<<<128, 256, 0, stream>>>(G, Wt + 524288, HF, 0);
    gemm_k1<1, bf16, 0, bf16><<<gg, 256, 0, stream>>>(V, h_wih_b, h_b_b, G, 2097152, 512, 32768, 1, 512, 1024);
    lstm_recur<<<128, 256, 0, stream>>>(G, Wt + 786432, HF + 256, 1);

    // ---- conv to kern [8][512][4096] fp32 (rows >=484 zero via padded weights) ----
    dim3 gc(8, 256);
    gemm_k1<1, bf16, 1, float><<<gc, 256, 0, stream>>>(HF, cw2, cb2, Kern, 2097152, 512, 32768, 1, 512, 512);

    // ---- softmax over the 484 channel dim ----
    softmax484<<<2048, 256, 0, stream>>>(Kern);

    // ---- global attention: patch gather + batched GEMM ----
    gather_patch<<<8192, 256, 0, stream>>>(x, Pch);
    dim3 gf(64, 32);
    final_gemm<<<gf, 256, 0, stream>>>(Pch, Kern, out);
}

// Round 3
// 3445.882 us; speedup vs baseline: 1.7170x; 1.7170x over previous
//
#include <hip/hip_runtime.h>
#include <hip/hip_bf16.h>
#include <math.h>

// ---------------------------------------------------------------------------
// PicanetG: Renet (2x BiLSTM, HID=256) + 1x1 conv(484) + softmax + attention.
// Round 2: MFMA weight-stationary LSTM recurrence (the 70% chunk in R1 profile).
//   B=8, C=512, H=W=64, HID=256. Output [8,512,64,64] fp32.
//
// ws layouts (float-offset units):
//  FUSED (ws >= 202,377,216 B): Gf@0, Gb@16777216 (bf16 64 MiB each),
//     V@33554432, HF@41943040 (bf16 32 MiB each), cw2@50331648, cb2@50593792.
//     Kern fp32 aliases Gf; Pch fp32 aliases V.
//  SERIAL (ws >= 135,268,352 B): G@0 (64 MiB), V@16777216, HF@25165824,
//     cw2@33554432, cb2@33816576. Kern aliases G; Pch aliases V.
// ---------------------------------------------------------------------------

typedef __hip_bfloat16 bf16;
typedef short short8 __attribute__((ext_vector_type(8)));
typedef float f4 __attribute__((ext_vector_type(4)));

__device__ __forceinline__ float toF(float v) { return v; }
__device__ __forceinline__ float toF(bf16 v)  { return __bfloat162float(v); }
__device__ __forceinline__ unsigned short bfbits(float f) {
    bf16 h = __float2bfloat16(f);
    return *reinterpret_cast<unsigned short*>(&h);
}
__device__ __forceinline__ float bf2f(unsigned short u) {
    union { unsigned int i; float f; } x; x.i = ((unsigned int)u) << 16; return x.f;
}
__device__ __forceinline__ float sigm(float x) {
    float e = __expf(-x);              // x->+inf: e=0 -> 1; x->-inf: e=inf -> 0
    return 1.0f / (1.0f + e);
}
__device__ __forceinline__ float tanh_fast(float x) {
    float x2 = fminf(fmaxf(2.0f * x, -30.0f), 30.0f);
    float e = __expf(x2);
    return (e - 1.0f) / (e + 1.0f);
}

// ---------------------------------------------------------------------------
// prep: zero-pad conv weights to [512][512] and conv bias to [512].
// ---------------------------------------------------------------------------
__global__ __launch_bounds__(256)
void prep_kernel(const float* __restrict__ cw, const float* __restrict__ cb,
                 float* __restrict__ cw2, float* __restrict__ cb2)
{
    int idx = blockIdx.x * 256 + threadIdx.x;
    if (idx < 262144) {
        int o = idx >> 9, k = idx & 511;
        cw2[idx] = (o < 484) ? cw[o * 512 + k] : 0.f;
    } else if (idx < 262144 + 512) {
        int o = idx - 262144;
        cb2[o] = (o < 484) ? cb[o] : 0.f;
    }
}

// ---------------------------------------------------------------------------
// Generic GEMM:  out[n,g] = sum_k A[n,k] * W[g,k] + bias[g]   (fp32 accum)
// A address: f(n) = (n>>12)*sA + ((n>>6)&63)*s1 + (n&63)*s0, element k at +k*sK.
// AMODE 0: lanes contiguous along n (phase V: x input fp32, sK=4096)
// AMODE 1: lanes contiguous along k (phase H / conv: bf16 input, sK=1)
// OMODE 0: out[n*Ncols + g]  (bf16 gate buffer)
// OMODE 1: out[(n>>12)*2097152 + g*4096 + (n&4095)]  (fp32 kern layout)
// ---------------------------------------------------------------------------
template<int AMODE, typename TA, int OMODE, typename TO>
__global__ __launch_bounds__(256)
void gemm_k1(const TA* __restrict__ A, const float* __restrict__ W,
             const float* __restrict__ bias, TO* __restrict__ out,
             int sA, int s1, int s0, int sK, int ldw, int Ncols)
{
    __shared__ float As[16][132];
    __shared__ float Bs[16][68];
    const int tid = threadIdx.x;
    const int g0 = blockIdx.x << 6;
    const int n0 = blockIdx.y << 7;
    const int tm = tid & 15, tn = tid >> 4;
    float acc[8][4];
    #pragma unroll
    for (int i = 0; i < 8; ++i)
        #pragma unroll
        for (int j = 0; j < 4; ++j) acc[i][j] = 0.f;

    for (int k0 = 0; k0 < 512; k0 += 16) {
        if (AMODE == 0) {
            int ln = tid & 127;
            int n  = n0 + ln;
            long fa = (long)(n >> 12) * sA + (long)((n >> 6) & 63) * s1 + (long)(n & 63) * s0;
            int lk = tid >> 7;
            #pragma unroll
            for (int r = 0; r < 8; ++r) {
                int kk = lk + (r << 1);
                As[kk][ln] = toF(A[fa + (long)(k0 + kk) * sK]);
            }
        } else {
            int lk = tid & 15, ln0 = tid >> 4;
            #pragma unroll
            for (int r = 0; r < 8; ++r) {
                int n = n0 + ln0 + (r << 4);
                long fa = (long)(n >> 12) * sA + (long)((n >> 6) & 63) * s1 + (long)(n & 63) * s0;
                As[lk][ln0 + (r << 4)] = toF(A[fa + (long)(k0 + lk) * sK]);
            }
        }
        {
            int lk = tid & 15, lg = tid >> 4;
            #pragma unroll
            for (int r = 0; r < 4; ++r) {
                int g = g0 + lg + (r << 4);
                Bs[lk][lg + (r << 4)] = W[(long)g * ldw + k0 + lk];
            }
        }
        __syncthreads();
        #pragma unroll
        for (int kk = 0; kk < 16; ++kk) {
            float4 a0 = *(const float4*)&As[kk][tm << 2];
            float4 a1 = *(const float4*)&As[kk][(tm << 2) + 64];
            float4 bf = *(const float4*)&Bs[kk][tn << 2];
            float av[8] = {a0.x,a0.y,a0.z,a0.w,a1.x,a1.y,a1.z,a1.w};
            float bv[4] = {bf.x,bf.y,bf.z,bf.w};
            #pragma unroll
            for (int i = 0; i < 8; ++i)
                #pragma unroll
                for (int j = 0; j < 4; ++j)
                    acc[i][j] += av[i] * bv[j];
        }
        __syncthreads();
    }

    float bvals[4];
    #pragma unroll
    for (int j = 0; j < 4; ++j) bvals[j] = bias[g0 + (tn << 2) + j];

    #pragma unroll
    for (int i = 0; i < 8; ++i) {
        int m = n0 + (tm << 2) + (i & 3) + ((i >> 2) << 6);
        if (OMODE == 0) {
            ushort4 u;
            u.x = bfbits(acc[i][0] + bvals[0]);
            u.y = bfbits(acc[i][1] + bvals[1]);
            u.z = bfbits(acc[i][2] + bvals[2]);
            u.w = bfbits(acc[i][3] + bvals[3]);
            *(ushort4*)&out[(long)m * Ncols + g0 + (tn << 2)] = u;
        } else {
            long ob = (long)(m >> 12) * 2097152 + (m & 4095);
            #pragma unroll
            for (int j = 0; j < 4; ++j)
                ((float*)out)[ob + (long)(g0 + (tn << 2) + j) * 4096] = acc[i][j] + bvals[j];
        }
    }
}

// ---------------------------------------------------------------------------
// MFMA weight-stationary LSTM recurrence.
// Grid: 64 WGs fused (dir = bid>>5) or 32 WGs with dir_force. 1024 thr = 16 waves.
// WG owns 16 sequences. Wave wv owns hidden slice [16*wv, 16*wv+16).
// B-fragments (Whh, bf16) register-resident: wfrag[gate q][K-tile kt].
//   B lane map: col g = q*256+wv*16+(lane&15), k = kt*32+(lane>>4)*8+j.
// A-fragments from XOR-swizzled h LDS (double-buffered), same k map.
// C/D: col = lane&15, row = (lane>>4)*4 + reg  [m89].
// Epilogue in-register: lane holds i,f,g,o for (seq row, hid col); c in VGPRs.
// G: [512 seq][64 t][1024 g] bf16 pre-activations (input proj + bias).
// Out: h at [(seq*64+t)*512 + dir*256 + j], bf16.
// ---------------------------------------------------------------------------
__global__ __launch_bounds__(1024, 4)
void lstm_recur_mfma(const bf16* __restrict__ Gf, const bf16* __restrict__ Gb,
                     const float* __restrict__ Wf, const float* __restrict__ Wb,
                     bf16* __restrict__ Out, int dir_force)
{
    __shared__ char hraw[16384];   // [2][16 seq][256 k] bf16, xor-swizzled
    const int tid = threadIdx.x;
    const int wv = tid >> 6;       // 0..15
    const int l  = tid & 63;
    const int lm = l & 15, lg = l >> 4;

    int dir, sblk;
    if (dir_force >= 0) { dir = dir_force; sblk = blockIdx.x; }
    else               { dir = blockIdx.x >> 5; sblk = blockIdx.x & 31; }
    const bf16*  G  = dir ? Gb : Gf;
    const float* WH = dir ? Wb : Wf;
    const int s0 = sblk << 4;
    const int dirOff = dir << 8;

    // ---- load Whh B-fragments (one-time, register-resident) ----
    short8 wfrag[4][8];
    #pragma unroll
    for (int q = 0; q < 4; ++q) {
        int g = q * 256 + wv * 16 + lm;
        const float* wr = WH + (long)g * 256 + lg * 8;
        #pragma unroll
        for (int kt = 0; kt < 8; ++kt) {
            const float* p = wr + kt * 32;
            short8 w;
            #pragma unroll
            for (int j = 0; j < 8; ++j) w[j] = (short)bfbits(p[j]);
            wfrag[q][kt] = w;
        }
    }

    // zero both h buffers
    {
        unsigned int* hb = (unsigned int*)hraw;
        #pragma unroll
        for (int r = 0; r < 4; ++r) hb[tid + r * 1024] = 0u;
    }

    float cst[4] = {0.f, 0.f, 0.f, 0.f};

    // per-lane G base: seq = s0 + lg*4 + r, g = q*256 + wv*16 + lm
    const bf16* Gbase = G + (long)(s0 + lg * 4) * 65536 + wv * 16 + lm;

    // preload step-0 gate pre-acts
    int t0 = dir ? 63 : 0;
    unsigned short u[16];
    #pragma unroll
    for (int q = 0; q < 4; ++q)
        #pragma unroll
        for (int r = 0; r < 4; ++r)
            u[q * 4 + r] = *(const unsigned short*)(Gbase + (long)r * 65536 + t0 * 1024 + q * 256);

    __syncthreads();

    for (int step = 0; step < 64; ++step) {
        const int t = dir ? (63 - step) : step;
        const int rbuf = (step & 1) ? 8192 : 0;
        const int wbuf = 8192 - rbuf;

        // A-fragments: h of previous step (row = lm = seq, swizzled)
        short8 af[8];
        {
            const char* hb = hraw + rbuf;
            int swz  = (lm & 7) << 4;
            int base = lm * 512 + lg * 16;
            #pragma unroll
            for (int kt = 0; kt < 8; ++kt)
                af[kt] = *(const short8*)(hb + ((base + kt * 64) ^ swz));
        }

        // init acc from gate pre-activations
        f4 acc[4];
        #pragma unroll
        for (int q = 0; q < 4; ++q) {
            #pragma unroll
            for (int r = 0; r < 4; ++r) acc[q][r] = bf2f(u[q * 4 + r]);
        }

        // prefetch next step's G (hidden under MFMA + epilogue)
        int sn = (step < 63) ? step + 1 : 63;
        int tn = dir ? (63 - sn) : sn;
        #pragma unroll
        for (int q = 0; q < 4; ++q)
            #pragma unroll
            for (int r = 0; r < 4; ++r)
                u[q * 4 + r] = *(const unsigned short*)(Gbase + (long)r * 65536 + tn * 1024 + q * 256);

        // h @ Whh^T
        #pragma unroll
        for (int kt = 0; kt < 8; ++kt) {
            #pragma unroll
            for (int q = 0; q < 4; ++q)
                acc[q] = __builtin_amdgcn_mfma_f32_16x16x32_bf16(af[kt], wfrag[q][kt], acc[q], 0, 0, 0);
        }

        // LSTM cell epilogue, fully in-register
        unsigned short hout[4];
        #pragma unroll
        for (int r = 0; r < 4; ++r) {
            float ii = sigm(acc[0][r]);
            float ff = sigm(acc[1][r]);
            float gg = tanh_fast(acc[2][r]);
            float oo = sigm(acc[3][r]);
            float c  = ff * cst[r] + ii * gg;
            cst[r] = c;
            float h  = oo * tanh_fast(c);
            hout[r] = bfbits(h);
        }

        // write h: LDS (next step) + global (bilstm output)
        {
            char* hb = hraw + wbuf;
            int j = wv * 16 + lm;
            #pragma unroll
            for (int r = 0; r < 4; ++r) {
                int seq = lg * 4 + r;
                *(unsigned short*)(hb + ((seq * 512 + j * 2) ^ ((seq & 7) << 4))) = hout[r];
                long off = ((long)(s0 + seq) * 64 + t) * 512 + dirOff + j;
                ((unsigned short*)Out)[off] = hout[r];
            }
        }
        __syncthreads();
    }
}

// ---------------------------------------------------------------------------
// Softmax over o=0..483 of kern [8][512][4096] fp32 (rows 484..511 stay 0).
// ---------------------------------------------------------------------------
__global__ __launch_bounds__(256)
void softmax484(float* __restrict__ kern)
{
    __shared__ float tile[484][16];
    __shared__ float red[16][17];
    __shared__ float mx[16], inv[16];
    const int b  = blockIdx.x >> 8;
    const int p0 = (blockIdx.x & 255) << 4;
    float* base = kern + (long)b * 2097152 + p0;
    const int pp = threadIdx.x & 15, oo = threadIdx.x >> 4;

    float pm = -3.4e38f;
    #pragma unroll 4
    for (int r = 0; r < 31; ++r) {
        int o = oo + (r << 4);
        if (o < 484) {
            float v = base[(long)o * 4096 + pp];
            tile[o][pp] = v;
            pm = fmaxf(pm, v);
        }
    }
    red[oo][pp] = pm;
    __syncthreads();
    if (oo == 0) {
        float m = red[0][pp];
        #pragma unroll
        for (int q = 1; q < 16; ++q) m = fmaxf(m, red[q][pp]);
        mx[pp] = m;
    }
    __syncthreads();
    float m = mx[pp];
    float ps = 0.f;
    #pragma unroll 4
    for (int r = 0; r < 31; ++r) {
        int o = oo + (r << 4);
        if (o < 484) {
            float e = __expf(tile[o][pp] - m);
            tile[o][pp] = e;
            ps += e;
        }
    }
    red[oo][pp] = ps;
    __syncthreads();
    if (oo == 0) {
        float s = 0.f;
        #pragma unroll
        for (int q = 0; q < 16; ++q) s += red[q][pp];
        inv[pp] = 1.f / s;
    }
    __syncthreads();
    float iv = inv[pp];
    #pragma unroll 4
    for (int r = 0; r < 31; ++r) {
        int o = oo + (r << 4);
        if (o < 484) base[(long)o * 4096 + pp] = tile[o][pp] * iv;
    }
}

// ---------------------------------------------------------------------------
// Gather dilated patch: Pch[b][c][o] = x[b, c, 3*(o/22), 3*(o%22)], 0-pad o>=484.
// ---------------------------------------------------------------------------
__global__ __launch_bounds__(256)
void gather_patch(const float* __restrict__ x, float* __restrict__ Pch)
{
    int idx = blockIdx.x * 256 + threadIdx.x;
    if (idx >= 2097152) return;
    int o = idx & 511, c = (idx >> 9) & 511, b = idx >> 18;
    float v = 0.f;
    if (o < 484) {
        int i = o / 22, jj = o - i * 22;
        v = x[(long)b * 2097152 + (long)c * 4096 + i * 192 + jj * 3];
    }
    Pch[idx] = v;
}

// ---------------------------------------------------------------------------
// Final attention GEMM: out[b*512+c][p] = sum_k Pch[(b*512+c)*512+k] * kern[b][k][p]
// ---------------------------------------------------------------------------
__global__ __launch_bounds__(256)
void final_gemm(const float* __restrict__ Pch, const float* __restrict__ kern,
                float* __restrict__ out)
{
    __shared__ float As[16][132];
    __shared__ float Bs[16][68];
    const int tid = threadIdx.x;
    const int p0 = blockIdx.x << 6;
    const int n0 = blockIdx.y << 7;
    const int b  = n0 >> 9;
    const float* Bb = kern + (long)b * 2097152;
    const int tm = tid & 15, tn = tid >> 4;
    float acc[8][4];
    #pragma unroll
    for (int i = 0; i < 8; ++i)
        #pragma unroll
        for (int j = 0; j < 4; ++j) acc[i][j] = 0.f;

    for (int k0 = 0; k0 < 512; k0 += 16) {
        {
            int lk = tid & 15, ln0 = tid >> 4;
            #pragma unroll
            for (int r = 0; r < 8; ++r) {
                int n = n0 + ln0 + (r << 4);
                As[lk][ln0 + (r << 4)] = Pch[(long)n * 512 + k0 + lk];
            }
        }
        {
            int lp = tid & 63, lkb = tid >> 6;
            #pragma unroll
            for (int r = 0; r < 4; ++r) {
                int kk = lkb + (r << 2);
                Bs[kk][lp] = Bb[(long)(k0 + kk) * 4096 + p0 + lp];
            }
        }
        __syncthreads();
        #pragma unroll
        for (int kk = 0; kk < 16; ++kk) {
            float4 a0 = *(const float4*)&As[kk][tm << 2];
            float4 a1 = *(const float4*)&As[kk][(tm << 2) + 64];
            float4 bf = *(const float4*)&Bs[kk][tn << 2];
            float av[8] = {a0.x,a0.y,a0.z,a0.w,a1.x,a1.y,a1.z,a1.w};
            float bv[4] = {bf.x,bf.y,bf.z,bf.w};
            #pragma unroll
            for (int i = 0; i < 8; ++i)
                #pragma unroll
                for (int j = 0; j < 4; ++j)
                    acc[i][j] += av[i] * bv[j];
        }
        __syncthreads();
    }
    #pragma unroll
    for (int i = 0; i < 8; ++i) {
        int m = n0 + (tm << 2) + (i & 3) + ((i >> 2) << 6);
        float4 v4 = make_float4(acc[i][0], acc[i][1], acc[i][2], acc[i][3]);
        *(float4*)&out[(long)m * 4096 + p0 + (tn << 2)] = v4;
    }
}

// ---------------------------------------------------------------------------
extern "C" void kernel_launch(void* const* d_in, const int* in_sizes, int n_in,
                              void* d_out, int out_size, void* d_ws, size_t ws_size,
                              hipStream_t stream)
{
    const float* x        = (const float*)d_in[0];
    const float* v_wih_f  = (const float*)d_in[1];
    const float* v_whh_f  = (const float*)d_in[2];
    const float* v_b_f    = (const float*)d_in[3];
    const float* v_wih_b  = (const float*)d_in[4];
    const float* v_whh_b  = (const float*)d_in[5];
    const float* v_b_b    = (const float*)d_in[6];
    const float* h_wih_f  = (const float*)d_in[7];
    const float* h_whh_f  = (const float*)d_in[8];
    const float* h_b_f    = (const float*)d_in[9];
    const float* h_wih_b  = (const float*)d_in[10];
    const float* h_whh_b  = (const float*)d_in[11];
    const float* h_b_b    = (const float*)d_in[12];
    const float* conv_w   = (const float*)d_in[13];
    const float* conv_b   = (const float*)d_in[14];

    const size_t REQ_FUSED  = 50594304UL * 4UL;   // 202,377,216 B
    const size_t REQ_SERIAL = 33817088UL * 4UL;   // 135,268,352 B
    if (ws_size < REQ_SERIAL) return;             // clean-fail diagnostic
    const bool fused = (ws_size >= REQ_FUSED);

    float* base = (float*)d_ws;
    float* out  = (float*)d_out;
    dim3 gg(16, 256);
    dim3 gc(8, 256);
    dim3 gf(64, 32);

    if (fused) {
        bf16*  Gf   = (bf16*)d_ws;
        bf16*  Gb   = (bf16*)(base + 16777216);
        bf16*  V    = (bf16*)(base + 33554432);
        bf16*  HF   = (bf16*)(base + 41943040);
        float* cw2  = base + 50331648;
        float* cb2  = base + 50593792;
        float* Kern = (float*)d_ws;          // aliases Gf
        float* Pch  = base + 33554432;       // aliases V

        prep_kernel<<<1027, 256, 0, stream>>>(conv_w, conv_b, cw2, cb2);

        // vertical BiLSTM
        gemm_k1<0, float, 0, bf16><<<gg, 256, 0, stream>>>(x, v_wih_f, v_b_f, Gf, 2097152, 64, 1, 4096, 512, 1024);
        gemm_k1<0, float, 0, bf16><<<gg, 256, 0, stream>>>(x, v_wih_b, v_b_b, Gb, 2097152, 64, 1, 4096, 512, 1024);
        lstm_recur_mfma<<<64, 1024, 0, stream>>>(Gf, Gb, v_whh_f, v_whh_b, V, -1);

        // horizontal BiLSTM
        gemm_k1<1, bf16, 0, bf16><<<gg, 256, 0, stream>>>(V, h_wih_f, h_b_f, Gf, 2097152, 512, 32768, 1, 512, 1024);
        gemm_k1<1, bf16, 0, bf16><<<gg, 256, 0, stream>>>(V, h_wih_b, h_b_b, Gb, 2097152, 512, 32768, 1, 512, 1024);
        lstm_recur_mfma<<<64, 1024, 0, stream>>>(Gf, Gb, h_whh_f, h_whh_b, HF, -1);

        gemm_k1<1, bf16, 1, float><<<gc, 256, 0, stream>>>(HF, cw2, cb2, Kern, 2097152, 512, 32768, 1, 512, 512);
        softmax484<<<2048, 256, 0, stream>>>(Kern);
        gather_patch<<<8192, 256, 0, stream>>>(x, Pch);
        final_gemm<<<gf, 256, 0, stream>>>(Pch, Kern, out);
    } else {
        bf16*  G    = (bf16*)d_ws;
        bf16*  V    = (bf16*)(base + 16777216);
        bf16*  HF   = (bf16*)(base + 25165824);
        float* cw2  = base + 33554432;
        float* cb2  = base + 33816576;
        float* Kern = (float*)d_ws;          // aliases G
        float* Pch  = base + 16777216;       // aliases V

        prep_kernel<<<1027, 256, 0, stream>>>(conv_w, conv_b, cw2, cb2);

        // vertical BiLSTM
        gemm_k1<0, float, 0, bf16><<<gg, 256, 0, stream>>>(x, v_wih_f, v_b_f, G, 2097152, 64, 1, 4096, 512, 1024);
        lstm_recur_mfma<<<32, 1024, 0, stream>>>(G, G, v_whh_f, v_whh_f, V, 0);
        gemm_k1<0, float, 0, bf16><<<gg, 256, 0, stream>>>(x, v_wih_b, v_b_b, G, 2097152, 64, 1, 4096, 512, 1024);
        lstm_recur_mfma<<<32, 1024, 0, stream>>>(G, G, v_whh_b, v_whh_b, V, 1);

        // horizontal BiLSTM
        gemm_k1<1, bf16, 0, bf16><<<gg, 256, 0, stream>>>(V, h_wih_f, h_b_f, G, 2097152, 512, 32768, 1, 512, 1024);
        lstm_recur_mfma<<<32, 1024, 0, stream>>>(G, G, h_whh_f, h_whh_f, HF, 0);
        gemm_k1<1, bf16, 0, bf16><<<gg, 256, 0, stream>>>(V, h_wih_b, h_b_b, G, 2097152, 512, 32768, 1, 512, 1024);
        lstm_recur_mfma<<<32, 1024, 0, stream>>>(G, G, h_whh_b, h_whh_b, HF, 1);

        gemm_k1<1, bf16, 1, float><<<gc, 256, 0, stream>>>(HF, cw2, cb2, Kern, 2097152, 512, 32768, 1, 512, 512);
        softmax484<<<2048, 256, 0, stream>>>(Kern);
        gather_patch<<<8192, 256, 0, stream>>>(x, Pch);
        final_gemm<<<gf, 256, 0, stream>>>(Pch, Kern, out);
    }
}

// Round 4
// 1954.709 us; speedup vs baseline: 3.0268x; 1.7629x over previous
//
#include <hip/hip_runtime.h>
#include <hip/hip_bf16.h>
#include <math.h>

// ---------------------------------------------------------------------------
// PicanetG: Renet (2x BiLSTM, HID=256) + 1x1 conv(484) + softmax + attention.
// Round 3: all-MFMA pipeline.
//   - lstm4: 4 seq/WG weight-stationary recurrence, 256 WGs (full chip),
//     LDS bounce redistributes cell work to all 64 lanes (5 trans/wave/step).
//   - gemm_mfma: LDS-free bf16 MFMA GEMM (frags straight from L2) for the
//     4 gate GEMMs + conv + final attention GEMM.
//   - weights pre-cast to bf16 into d_out tail (dead until final GEMM).
//
// FUSED ws layout (float units), REQ = 50331648 fl = 201,326,592 B:
//   Gf @ 0         bf16 [32768][1024] (64 MiB); later convout fp32 [32768][512]
//   Gb @ 16777216  bf16 [32768][1024] (64 MiB); later kernT bf16 [8][4096][512] (32 MiB)
//   V  @ 33554432  bf16 [32768][512] (32 MiB); first xt bf16, later Pch bf16 [4096][512]
//   HF @ 41943040  bf16 [32768][512] (32 MiB)
// SERIAL ws layout, REQ = 33554432 fl = 134,217,728 B:
//   G @ 0 (64 MiB; later convout, then Pch), V @ 16777216 (later kernT),
//   xt/HF @ 25165824.
// d_out tail scratch (float offset from out): wt bf16 x4 @ +8388608,
//   cw2b bf16 @ +9437184, cb2 fp32 @ +9568256. All dead before final_gemm.
// ---------------------------------------------------------------------------

typedef __hip_bfloat16 bf16;
typedef short short8 __attribute__((ext_vector_type(8)));
typedef float f4 __attribute__((ext_vector_type(4)));

__device__ __forceinline__ unsigned short bfbits(float f) {
    bf16 h = __float2bfloat16(f);
    return *reinterpret_cast<unsigned short*>(&h);
}
__device__ __forceinline__ float bf2f(unsigned short u) {
    union { unsigned int i; float f; } x; x.i = ((unsigned int)u) << 16; return x.f;
}
__device__ __forceinline__ float sigm(float x) {
    return 1.0f / (1.0f + __expf(-x));
}
__device__ __forceinline__ float tanh_fast(float x) {
    float x2 = fminf(fmaxf(2.0f * x, -30.0f), 30.0f);
    float e = __expf(x2);
    return (e - 1.0f) / (e + 1.0f);
}

// ---------------------------------------------------------------------------
// prep_weights: cast 4 gate weight mats to bf16; zero-pad conv w/b.
// wt layout: [mat][1024 g][512 k] bf16.
// ---------------------------------------------------------------------------
__global__ __launch_bounds__(256)
void prep_weights(const float* __restrict__ w0, const float* __restrict__ w1,
                  const float* __restrict__ w2, const float* __restrict__ w3,
                  const float* __restrict__ cw, const float* __restrict__ cb,
                  bf16* __restrict__ wt, bf16* __restrict__ cw2b, float* __restrict__ cb2)
{
    int idx = blockIdx.x * 256 + threadIdx.x;
    if (idx < 2097152) {
        int mat = idx >> 19, rem = idx & 524287;
        const float* src = (mat == 0) ? w0 : (mat == 1) ? w1 : (mat == 2) ? w2 : w3;
        wt[idx] = __float2bfloat16(src[rem]);
    } else if (idx < 2097152 + 262144) {
        int r = idx - 2097152; int o = r >> 9, k = r & 511;
        cw2b[r] = __float2bfloat16((o < 484) ? cw[o * 512 + k] : 0.f);
    } else if (idx < 2097152 + 262144 + 512) {
        int o = idx - 2097152 - 262144;
        cb2[o] = (o < 484) ? cb[o] : 0.f;
    }
}

// ---------------------------------------------------------------------------
// xtrans: x [8][512][64][64] fp32 -> xt [b*4096 + h*64 + w][512 c] bf16.
// Block: (b, h, ctile of 64). LDS 64x65 transpose tile.
// ---------------------------------------------------------------------------
__global__ __launch_bounds__(256)
void xtrans(const float* __restrict__ x, bf16* __restrict__ xt)
{
    __shared__ float T[64][65];
    const int tid = threadIdx.x;
    const int bid = blockIdx.x;
    const int b = bid >> 9, h = (bid >> 3) & 63, ct = bid & 7;
    const int c0 = ct << 6;
    const float* xp = x + ((long)(b * 512 + c0) * 64 + h) * 64;
    const int wv = tid >> 6, wl = tid & 63;
    #pragma unroll
    for (int r = 0; r < 16; ++r) {
        int ci = wv + (r << 2);
        T[ci][wl] = xp[(long)ci * 4096 + wl];
    }
    __syncthreads();
    const int wr = tid >> 2, cj = (tid & 3) << 4;
    bf16* op = xt + ((long)(b * 4096 + h * 64 + wr) * 512) + c0 + cj;
    short8 v0, v1;
    #pragma unroll
    for (int i = 0; i < 8; ++i) v0[i] = (short)bfbits(T[cj + i][wr]);
    #pragma unroll
    for (int i = 0; i < 8; ++i) v1[i] = (short)bfbits(T[cj + 8 + i][wr]);
    *(short8*)op = v0;
    *(short8*)(op + 8) = v1;
}

// ---------------------------------------------------------------------------
// gemm_mfma: LDS-free bf16 MFMA GEMM. out[n][col] = sum_k A[arow(n)][k]*W[col][k].
// K=512 always. Block 256 thr = 4 waves; wave owns 32 rows; BM=128, BN=64.
// A-frag: row=lm, k=lg*8+j (16B loads from L2). B-frag: col=lm, same k map.
// D: row=lg*4+r, col=lm (verified fragment maps from the lstm kernel).
// MODE: 0=VERT (out bf16 [n][1024], bias, arow=n)
//       1=HORIZ(out bf16 [n][1024], bias, arow=swap(n))
//       2=CONV (out fp32 [n][512],  bias, arow=swap(n))
//       3=FINAL(out fp32 [n][4096], no bias, arow=n, per-b W = kernT+b*2097152)
// swap(n) = (n>>12)*4096 + (n&63)*64 + ((n>>6)&63).
// ---------------------------------------------------------------------------
template<int MODE>
__global__ __launch_bounds__(256)
void gemm_mfma(const bf16* __restrict__ A, const bf16* __restrict__ W,
               const float* __restrict__ bias, void* __restrict__ outp)
{
    const int tid = threadIdx.x;
    const int wv = tid >> 6, l = tid & 63;
    const int lm = l & 15, lg = l >> 4;
    const int g0 = blockIdx.x << 6;
    const int n0 = blockIdx.y << 7;

    const bf16* Wb = W;
    if (MODE == 3) Wb += (long)(n0 >> 9) * 2097152;   // per-b kernT

    // per-lane A offsets (elements) for the 2 M-frags
    int aoff[2];
    #pragma unroll
    for (int mf = 0; mf < 2; ++mf) {
        int n = n0 + wv * 32 + mf * 16 + lm;
        int arow;
        if (MODE == 1 || MODE == 2) arow = (n >> 12) * 4096 + (n & 63) * 64 + ((n >> 6) & 63);
        else                        arow = n;
        aoff[mf] = arow * 512 + lg * 8;
    }
    int boff[4];
    #pragma unroll
    for (int nf = 0; nf < 4; ++nf)
        boff[nf] = (g0 + nf * 16 + lm) * 512 + lg * 8;

    f4 acc[2][4];
    #pragma unroll
    for (int mf = 0; mf < 2; ++mf)
        #pragma unroll
        for (int nf = 0; nf < 4; ++nf)
            acc[mf][nf] = (f4){0.f, 0.f, 0.f, 0.f};

    short8 a[2], bq[4];
    #pragma unroll
    for (int mf = 0; mf < 2; ++mf) a[mf] = *(const short8*)(A + aoff[mf]);
    #pragma unroll
    for (int nf = 0; nf < 4; ++nf) bq[nf] = *(const short8*)(Wb + boff[nf]);

    #pragma unroll
    for (int ks = 0; ks < 16; ++ks) {
        short8 an[2], bn[4];
        if (ks < 15) {
            int k0 = (ks + 1) << 5;
            #pragma unroll
            for (int mf = 0; mf < 2; ++mf) an[mf] = *(const short8*)(A + aoff[mf] + k0);
            #pragma unroll
            for (int nf = 0; nf < 4; ++nf) bn[nf] = *(const short8*)(Wb + boff[nf] + k0);
        }
        #pragma unroll
        for (int mf = 0; mf < 2; ++mf)
            #pragma unroll
            for (int nf = 0; nf < 4; ++nf)
                acc[mf][nf] = __builtin_amdgcn_mfma_f32_16x16x32_bf16(a[mf], bq[nf], acc[mf][nf], 0, 0, 0);
        if (ks < 15) {
            #pragma unroll
            for (int mf = 0; mf < 2; ++mf) a[mf] = an[mf];
            #pragma unroll
            for (int nf = 0; nf < 4; ++nf) bq[nf] = bn[nf];
        }
    }

    float bv[4];
    if (MODE != 3) {
        #pragma unroll
        for (int nf = 0; nf < 4; ++nf) bv[nf] = bias[g0 + nf * 16 + lm];
    }

    #pragma unroll
    for (int mf = 0; mf < 2; ++mf) {
        #pragma unroll
        for (int nf = 0; nf < 4; ++nf) {
            const int col = g0 + nf * 16 + lm;
            #pragma unroll
            for (int r = 0; r < 4; ++r) {
                const int n = n0 + wv * 32 + mf * 16 + lg * 4 + r;
                float v = acc[mf][nf][r];
                if (MODE == 0 || MODE == 1)
                    ((unsigned short*)outp)[(long)n * 1024 + col] = bfbits(v + bv[nf]);
                else if (MODE == 2)
                    ((float*)outp)[(long)n * 512 + col] = v + bv[nf];
                else
                    ((float*)outp)[(long)n * 4096 + col] = v;
            }
        }
    }
}

// ---------------------------------------------------------------------------
// lstm4: weight-stationary MFMA recurrence, 4 sequences per WG.
// 1024 thr = 16 waves; wave wv owns hidden slice [16*wv, 16*wv+16), all 4 gates
// register-resident (wfrag[q][kt], 128 VGPR). h double-buffered in LDS
// (4 rows x 512B, XOR-swizzled). MFMA D rows 0-3 = the 4 seqs (rows 4-15
// discarded). Per-wave LDS bounce redistributes (seq,hid,q) to all 64 lanes:
// lane l handles cell (seq=l>>4, hid=l&15) -> 5 trans/lane/step.
// G [n=seq*64+t][1024] bf16; prefetch depth 2. Out h at [n][512]+dir*256.
// ---------------------------------------------------------------------------
__global__ __launch_bounds__(1024, 4)
void lstm4(const bf16* __restrict__ Gf, const bf16* __restrict__ Gb,
           const float* __restrict__ Wf, const float* __restrict__ Wb,
           bf16* __restrict__ Out, int dir_force)
{
    __shared__ char hraw[4096];        // [2 buf][4 seq][512B], swizzled
    __shared__ float bnc[16][256];     // per-wave bounce [seq][hid][q]
    const int tid = threadIdx.x;
    const int wv = tid >> 6, l = tid & 63;
    const int lm = l & 15, lg = l >> 4;
    const int seq = l >> 4, hid = l & 15;     // consumer-domain mapping
    const int j_l = wv * 16 + hid;

    int dir, sblk;
    if (dir_force >= 0) { dir = dir_force; sblk = blockIdx.x; }
    else               { dir = blockIdx.x >> 7; sblk = blockIdx.x & 127; }
    const bf16*  G  = dir ? Gb : Gf;
    const float* WH = dir ? Wb : Wf;
    const int s0 = sblk << 2;

    // Whh B-fragments: col g = q*256 + wv*16 + lm, k = kt*32 + lg*8 + j
    short8 wfrag[4][8];
    #pragma unroll
    for (int q = 0; q < 4; ++q) {
        int g = q * 256 + wv * 16 + lm;
        const float* wr = WH + (long)g * 256 + lg * 8;
        #pragma unroll
        for (int kt = 0; kt < 8; ++kt) {
            const float* p = wr + kt * 32;
            short8 w;
            #pragma unroll
            for (int j = 0; j < 8; ++j) w[j] = (short)bfbits(p[j]);
            wfrag[q][kt] = w;
        }
    }

    ((unsigned int*)hraw)[tid] = 0u;   // zero both h buffers (4096 B)

    float c = 0.f;
    const unsigned short* Gl = (const unsigned short*)G + (long)(s0 + seq) * 65536 + j_l;

    // prefetch steps 0 and 1
    unsigned short u[2][4];
    {
        int t0 = dir ? 63 : 0, t1 = dir ? 62 : 1;
        #pragma unroll
        for (int q = 0; q < 4; ++q) u[0][q] = Gl[t0 * 1024 + q * 256];
        #pragma unroll
        for (int q = 0; q < 4; ++q) u[1][q] = Gl[t1 * 1024 + q * 256];
    }
    __syncthreads();

    for (int step = 0; step < 64; ++step) {
        const int t = dir ? (63 - step) : step;
        const int cur = step & 1;
        const char* rb = hraw + (cur ? 2048 : 0);
        char* wb2 = hraw + (cur ? 0 : 2048);

        // A-fragments: row = lm&3 (dup for lm>=4), k = kt*32 + lg*8 + j
        short8 af[8];
        {
            const int row = lm & 3;
            const int rbase = row * 512;
            const int swz = row << 4;
            #pragma unroll
            for (int kt = 0; kt < 8; ++kt)
                af[kt] = *(const short8*)(rb + rbase + ((lg * 16 + kt * 64) ^ swz));
        }

        f4 acc[4];
        #pragma unroll
        for (int q = 0; q < 4; ++q) acc[q] = (f4){0.f, 0.f, 0.f, 0.f};
        #pragma unroll
        for (int kt = 0; kt < 8; ++kt)
            #pragma unroll
            for (int q = 0; q < 4; ++q)
                acc[q] = __builtin_amdgcn_mfma_f32_16x16x32_bf16(af[kt], wfrag[q][kt], acc[q], 0, 0, 0);

        // bounce: lanes lg==0 hold D rows 0-3 (the 4 seqs) at col lm
        if (lg == 0) {
            #pragma unroll
            for (int r = 0; r < 4; ++r) {
                f4 v; v[0] = acc[0][r]; v[1] = acc[1][r]; v[2] = acc[2][r]; v[3] = acc[3][r];
                *(f4*)&bnc[wv][(r * 16 + lm) * 4] = v;
            }
        }
        float4 pv = *(float4*)&bnc[wv][(seq * 16 + hid) * 4];

        // cell (one unit per lane)
        float gi = pv.x + bf2f(u[cur][0]);
        float gf = pv.y + bf2f(u[cur][1]);
        float gg = pv.z + bf2f(u[cur][2]);
        float go = pv.w + bf2f(u[cur][3]);
        float ii = sigm(gi), ff = sigm(gf), gc = tanh_fast(gg), oo = sigm(go);
        c = ff * c + ii * gc;
        float h = oo * tanh_fast(c);

        // prefetch step+2 into the consumed slot
        {
            int sp = step + 2;
            int tp = (sp < 64) ? (dir ? 63 - sp : sp) : t;
            #pragma unroll
            for (int q = 0; q < 4; ++q) u[cur][q] = Gl[tp * 1024 + q * 256];
        }

        // write h: LDS (next step) + global
        unsigned short hb = bfbits(h);
        *(unsigned short*)(wb2 + seq * 512 + ((j_l * 2) ^ (seq << 4))) = hb;
        ((unsigned short*)Out)[((long)(s0 + seq) * 64 + t) * 512 + (dir << 8) + j_l] = hb;
        __syncthreads();
    }
}

// ---------------------------------------------------------------------------
// softmax_rows: convout fp32 [32768][512] -> kernT bf16 [32768][512].
// One wave per row; softmax over cols 0..483, cols 484..511 -> 0.
// ---------------------------------------------------------------------------
__global__ __launch_bounds__(256)
void softmax_rows(const float* __restrict__ cin, bf16* __restrict__ kout)
{
    const int tid = threadIdx.x;
    const int row = blockIdx.x * 4 + (tid >> 6);
    const int l = tid & 63;
    const float* rp = cin + (long)row * 512 + l * 8;
    float v[8];
    *(float4*)&v[0] = *(const float4*)rp;
    *(float4*)&v[4] = *(const float4*)(rp + 4);
    float m = -3.4e38f;
    #pragma unroll
    for (int i = 0; i < 8; ++i) {
        int o = l * 8 + i;
        if (o < 484) m = fmaxf(m, v[i]);
    }
    #pragma unroll
    for (int d = 1; d < 64; d <<= 1) m = fmaxf(m, __shfl_xor(m, d));
    float e[8], s = 0.f;
    #pragma unroll
    for (int i = 0; i < 8; ++i) {
        int o = l * 8 + i;
        e[i] = (o < 484) ? __expf(v[i] - m) : 0.f;
        s += e[i];
    }
    #pragma unroll
    for (int d = 1; d < 64; d <<= 1) s += __shfl_xor(s, d);
    float inv = 1.f / s;
    short8 st;
    #pragma unroll
    for (int i = 0; i < 8; ++i) st[i] = (short)bfbits(e[i] * inv);
    *(short8*)(kout + (long)row * 512 + l * 8) = st;
}

// ---------------------------------------------------------------------------
// gather_patch: Pch[b*512+c][o] = bf16(x[b, c, 3*(o/22), 3*(o%22)]), 0 for o>=484.
// ---------------------------------------------------------------------------
__global__ __launch_bounds__(256)
void gather_patch(const float* __restrict__ x, bf16* __restrict__ Pch)
{
    int idx = blockIdx.x * 256 + threadIdx.x;
    if (idx >= 2097152) return;
    int o = idx & 511, c = (idx >> 9) & 511, b = idx >> 18;
    float v = 0.f;
    if (o < 484) {
        int i = o / 22, jj = o - i * 22;
        v = x[(long)b * 2097152 + (long)c * 4096 + i * 192 + jj * 3];
    }
    Pch[idx] = __float2bfloat16(v);
}

// ---------------------------------------------------------------------------
extern "C" void kernel_launch(void* const* d_in, const int* in_sizes, int n_in,
                              void* d_out, int out_size, void* d_ws, size_t ws_size,
                              hipStream_t stream)
{
    const float* x        = (const float*)d_in[0];
    const float* v_wih_f  = (const float*)d_in[1];
    const float* v_whh_f  = (const float*)d_in[2];
    const float* v_b_f    = (const float*)d_in[3];
    const float* v_wih_b  = (const float*)d_in[4];
    const float* v_whh_b  = (const float*)d_in[5];
    const float* v_b_b    = (const float*)d_in[6];
    const float* h_wih_f  = (const float*)d_in[7];
    const float* h_whh_f  = (const float*)d_in[8];
    const float* h_b_f    = (const float*)d_in[9];
    const float* h_wih_b  = (const float*)d_in[10];
    const float* h_whh_b  = (const float*)d_in[11];
    const float* h_b_b    = (const float*)d_in[12];
    const float* conv_w   = (const float*)d_in[13];
    const float* conv_b   = (const float*)d_in[14];

    const size_t REQ_FUSED  = 50331648UL * 4UL;   // 201,326,592 B
    const size_t REQ_SERIAL = 33554432UL * 4UL;   // 134,217,728 B
    if (ws_size < REQ_SERIAL) return;             // clean-fail diagnostic
    const bool fused = (ws_size >= REQ_FUSED);

    float* wsf = (float*)d_ws;
    float* out = (float*)d_out;

    // weight scratch in d_out tail (dead before final_gemm writes out)
    bf16*  wt    = (bf16*)(out + 8388608);        // 4 x [1024][512]
    bf16*  cw2b  = (bf16*)(out + 8388608 + 1048576);
    float* cb2   = out + 8388608 + 1048576 + 131072;

    prep_weights<<<9220, 256, 0, stream>>>(v_wih_f, v_wih_b, h_wih_f, h_wih_b,
                                           conv_w, conv_b, wt, cw2b, cb2);
    bf16* wt_vf = wt;
    bf16* wt_vb = wt + 524288;
    bf16* wt_hf = wt + 1048576;
    bf16* wt_hb = wt + 1572864;

    dim3 gG(16, 256);   // gate GEMMs: N=1024, M=32768
    dim3 gC(8, 256);    // conv:       N=512,  M=32768
    dim3 gF(64, 32);    // final:      N=4096, M=4096

    if (fused) {
        bf16*  Gf    = (bf16*)d_ws;
        bf16*  Gb    = (bf16*)(wsf + 16777216);
        bf16*  V     = (bf16*)(wsf + 33554432);
        bf16*  HF    = (bf16*)(wsf + 41943040);
        bf16*  xt    = V;                      // xt dead after vertical GEMMs
        float* convo = (float*)d_ws;           // aliases Gf
        bf16*  kernT = Gb;                     // aliases Gb (32 of 64 MiB)
        bf16*  Pch   = V;                      // aliases V

        xtrans<<<4096, 256, 0, stream>>>(x, xt);
        gemm_mfma<0><<<gG, 256, 0, stream>>>(xt, wt_vf, v_b_f, Gf);
        gemm_mfma<0><<<gG, 256, 0, stream>>>(xt, wt_vb, v_b_b, Gb);
        lstm4<<<256, 1024, 0, stream>>>(Gf, Gb, v_whh_f, v_whh_b, V, -1);

        gemm_mfma<1><<<gG, 256, 0, stream>>>(V, wt_hf, h_b_f, Gf);
        gemm_mfma<1><<<gG, 256, 0, stream>>>(V, wt_hb, h_b_b, Gb);
        lstm4<<<256, 1024, 0, stream>>>(Gf, Gb, h_whh_f, h_whh_b, HF, -1);

        gemm_mfma<2><<<gC, 256, 0, stream>>>(HF, cw2b, cb2, convo);
        softmax_rows<<<8192, 256, 0, stream>>>(convo, kernT);
        gather_patch<<<8192, 256, 0, stream>>>(x, Pch);
        gemm_mfma<3><<<gF, 256, 0, stream>>>(Pch, kernT, nullptr, out);
    } else {
        bf16*  G     = (bf16*)d_ws;
        bf16*  V     = (bf16*)(wsf + 16777216);
        bf16*  xt    = (bf16*)(wsf + 25165824); // shares with HF (xt dead first)
        bf16*  HF    = xt;
        float* convo = (float*)d_ws;            // aliases G
        bf16*  kernT = V;                       // aliases V
        bf16*  Pch   = (bf16*)d_ws;             // aliases convo after softmax

        xtrans<<<4096, 256, 0, stream>>>(x, xt);
        gemm_mfma<0><<<gG, 256, 0, stream>>>(xt, wt_vf, v_b_f, G);
        lstm4<<<128, 1024, 0, stream>>>(G, G, v_whh_f, v_whh_f, V, 0);
        gemm_mfma<0><<<gG, 256, 0, stream>>>(xt, wt_vb, v_b_b, G);
        lstm4<<<128, 1024, 0, stream>>>(G, G, v_whh_b, v_whh_b, V, 1);

        gemm_mfma<1><<<gG, 256, 0, stream>>>(V, wt_hf, h_b_f, G);
        lstm4<<<128, 1024, 0, stream>>>(G, G, h_whh_f, h_whh_f, HF, 0);
        gemm_mfma<1><<<gG, 256, 0, stream>>>(V, wt_hb, h_b_b, G);
        lstm4<<<128, 1024, 0, stream>>>(G, G, h_whh_b, h_whh_b, HF, 1);

        gemm_mfma<2><<<gC, 256, 0, stream>>>(HF, cw2b, cb2, convo);
        softmax_rows<<<8192, 256, 0, stream>>>(convo, kernT);
        gather_patch<<<8192, 256, 0, stream>>>(x, Pch);
        gemm_mfma<3><<<gF, 256, 0, stream>>>(Pch, kernT, nullptr, out);
    }
}

// Round 5
// 1140.321 us; speedup vs baseline: 5.1884x; 1.7142x over previous
//
#include <hip/hip_runtime.h>
#include <hip/hip_bf16.h>
#include <hip/hip_fp8.h>
#include <math.h>

// ---------------------------------------------------------------------------
// PicanetG: Renet (2x BiLSTM, HID=256) + 1x1 conv(484) + softmax + attention.
// Round 4: spill-free fp8 weight-stationary recurrence + layout fixes.
//   - lstm_fp8: Whh and h in e4m3, mfma_f32_16x16x32_fp8_fp8; wfrag 64 VGPR
//     -> fits the 128-reg/wave cliff at 16 waves/CU with room to spare.
//   - G gate buffer interleaved [row][j 256][q 4]: one ushort4 load per lane
//     per step (named prefetch regs uA/uB, step loop unrolled by 2).
//   - lstm writes h "swapped-on-write" so all downstream GEMMs read A rows
//     contiguously (arow == n everywhere).
//
// FUSED ws (float units), REQ = 50331648 fl = 201,326,592 B:
//   Gf @ 0         bf16 [32768][1024] (64 MiB); later convout fp32 [32768][512]
//   Gb @ 16777216  bf16 (64 MiB); later kernT bf16 [8][4096][512] (32 MiB)
//   V  @ 33554432  bf16 [32768][512] (32 MiB); first xt, later Pch
//   HF @ 41943040  bf16 [32768][512] (32 MiB)
// SERIAL ws, REQ = 134,217,728 B: G@0, V@16777216, xt/HF@25165824.
// d_out tail scratch (fl offset): wt bf16 @ +8388608, cw2b @ +9437184,
//   cb2 @ +9568256, wq fp8 @ +9568768. All consumed before final_gemm.
// ---------------------------------------------------------------------------

typedef __hip_bfloat16 bf16;
typedef short short8 __attribute__((ext_vector_type(8)));
typedef float f4 __attribute__((ext_vector_type(4)));

__device__ __forceinline__ unsigned short bfbits(float f) {
    bf16 h = __float2bfloat16(f);
    return *reinterpret_cast<unsigned short*>(&h);
}
__device__ __forceinline__ float bf2f(unsigned short u) {
    union { unsigned int i; float f; } x; x.i = ((unsigned int)u) << 16; return x.f;
}
__device__ __forceinline__ unsigned char f2fp8(float f) {
    __hip_fp8_e4m3 q(f);
    return *reinterpret_cast<unsigned char*>(&q);
}
__device__ __forceinline__ float sigm(float x) {
    return 1.0f / (1.0f + __expf(-x));
}
__device__ __forceinline__ float tanh_fast(float x) {
    float x2 = fminf(fmaxf(2.0f * x, -30.0f), 30.0f);
    float e = __expf(x2);
    return (e - 1.0f) / (e + 1.0f);
}

// ---------------------------------------------------------------------------
// prep_weights: wt bf16 [4][1024 g][512 k]; cw2b [512][512]; cb2 [512];
//               wq e4m3 [4][1024 g][256 k].
// ---------------------------------------------------------------------------
__global__ __launch_bounds__(256)
void prep_weights(const float* __restrict__ w0, const float* __restrict__ w1,
                  const float* __restrict__ w2, const float* __restrict__ w3,
                  const float* __restrict__ cw, const float* __restrict__ cb,
                  const float* __restrict__ u0, const float* __restrict__ u1,
                  const float* __restrict__ u2, const float* __restrict__ u3,
                  bf16* __restrict__ wt, bf16* __restrict__ cw2b,
                  float* __restrict__ cb2, unsigned char* __restrict__ wq)
{
    int idx = blockIdx.x * 256 + threadIdx.x;
    if (idx < 2097152) {
        int mat = idx >> 19, rem = idx & 524287;
        const float* src = (mat == 0) ? w0 : (mat == 1) ? w1 : (mat == 2) ? w2 : w3;
        wt[idx] = __float2bfloat16(src[rem]);
    } else if (idx < 2097152 + 262144) {
        int r = idx - 2097152; int o = r >> 9, k = r & 511;
        cw2b[r] = __float2bfloat16((o < 484) ? cw[o * 512 + k] : 0.f);
    } else if (idx < 2097152 + 262144 + 512) {
        int o = idx - 2097152 - 262144;
        cb2[o] = (o < 484) ? cb[o] : 0.f;
    } else if (idx < 2097152 + 262144 + 512 + 1048576) {
        int r = idx - 2097152 - 262144 - 512;
        int mat = r >> 18, rem = r & 262143;
        const float* src = (mat == 0) ? u0 : (mat == 1) ? u1 : (mat == 2) ? u2 : u3;
        wq[r] = f2fp8(src[rem]);
    }
}

// ---------------------------------------------------------------------------
// xtrans: x [8][512][64][64] fp32 -> xt [b*4096 + h*64 + w][512 c] bf16.
// ---------------------------------------------------------------------------
__global__ __launch_bounds__(256)
void xtrans(const float* __restrict__ x, bf16* __restrict__ xt)
{
    __shared__ float T[64][65];
    const int tid = threadIdx.x;
    const int bid = blockIdx.x;
    const int b = bid >> 9, h = (bid >> 3) & 63, ct = bid & 7;
    const int c0 = ct << 6;
    const float* xp = x + ((long)(b * 512 + c0) * 64 + h) * 64;
    const int wv = tid >> 6, wl = tid & 63;
    #pragma unroll
    for (int r = 0; r < 16; ++r) {
        int ci = wv + (r << 2);
        T[ci][wl] = xp[(long)ci * 4096 + wl];
    }
    __syncthreads();
    const int wr = tid >> 2, cj = (tid & 3) << 4;
    bf16* op = xt + ((long)(b * 4096 + h * 64 + wr) * 512) + c0 + cj;
    short8 v0, v1;
    #pragma unroll
    for (int i = 0; i < 8; ++i) v0[i] = (short)bfbits(T[cj + i][wr]);
    #pragma unroll
    for (int i = 0; i < 8; ++i) v1[i] = (short)bfbits(T[cj + 8 + i][wr]);
    *(short8*)op = v0;
    *(short8*)(op + 8) = v1;
}

// ---------------------------------------------------------------------------
// gemm_mfma: LDS-free bf16 MFMA GEMM, K=512, A rows contiguous (arow = n).
// Block 256 thr = 4 waves; BM=128, BN=64; per-wave 32 rows (2 Mfrags).
// A-frag: row=lm, k=lg*8+j; B-frag: col=lm, same k map; D: row=lg*4+r, col=lm.
// MODE 0 GATE : W rows g = nf*256 + (bx*16+lm); out bf16 interleaved
//               [n][j*4+q] (ushort4 per (n,j)); bias[nf*256+j].
// MODE 1 CONV : out fp32 [n][512] + bias.
// MODE 2 FINAL: out fp32 [n][4096], per-b W (kernT + b*2097152), no bias.
// ---------------------------------------------------------------------------
template<int MODE>
__global__ __launch_bounds__(256)
void gemm_mfma(const bf16* __restrict__ A, const bf16* __restrict__ W,
               const float* __restrict__ bias, void* __restrict__ outp)
{
    const int tid = threadIdx.x;
    const int wv = tid >> 6, l = tid & 63;
    const int lm = l & 15, lg = l >> 4;
    const int n0 = blockIdx.y << 7;

    const bf16* Wb = W;
    long boff[4];
    int jcol = 0, g0 = 0;
    if (MODE == 0) {
        jcol = (blockIdx.x << 4) + lm;
        #pragma unroll
        for (int nf = 0; nf < 4; ++nf)
            boff[nf] = (long)(nf * 256 + jcol) * 512 + lg * 8;
    } else {
        g0 = blockIdx.x << 6;
        if (MODE == 2) Wb += (long)(n0 >> 9) * 2097152;
        #pragma unroll
        for (int nf = 0; nf < 4; ++nf)
            boff[nf] = (long)(g0 + nf * 16 + lm) * 512 + lg * 8;
    }
    long aoff[2];
    #pragma unroll
    for (int mf = 0; mf < 2; ++mf)
        aoff[mf] = (long)(n0 + wv * 32 + mf * 16 + lm) * 512 + lg * 8;

    f4 acc[2][4];
    #pragma unroll
    for (int mf = 0; mf < 2; ++mf)
        #pragma unroll
        for (int nf = 0; nf < 4; ++nf)
            acc[mf][nf] = (f4){0.f, 0.f, 0.f, 0.f};

    short8 a[2], bq[4];
    #pragma unroll
    for (int mf = 0; mf < 2; ++mf) a[mf] = *(const short8*)(A + aoff[mf]);
    #pragma unroll
    for (int nf = 0; nf < 4; ++nf) bq[nf] = *(const short8*)(Wb + boff[nf]);

    #pragma unroll
    for (int ks = 0; ks < 16; ++ks) {
        short8 an[2], bn[4];
        if (ks < 15) {
            int k0 = (ks + 1) << 5;
            #pragma unroll
            for (int mf = 0; mf < 2; ++mf) an[mf] = *(const short8*)(A + aoff[mf] + k0);
            #pragma unroll
            for (int nf = 0; nf < 4; ++nf) bn[nf] = *(const short8*)(Wb + boff[nf] + k0);
        }
        #pragma unroll
        for (int mf = 0; mf < 2; ++mf)
            #pragma unroll
            for (int nf = 0; nf < 4; ++nf)
                acc[mf][nf] = __builtin_amdgcn_mfma_f32_16x16x32_bf16(a[mf], bq[nf], acc[mf][nf], 0, 0, 0);
        if (ks < 15) {
            #pragma unroll
            for (int mf = 0; mf < 2; ++mf) a[mf] = an[mf];
            #pragma unroll
            for (int nf = 0; nf < 4; ++nf) bq[nf] = bn[nf];
        }
    }

    float bv[4];
    if (MODE != 2) {
        #pragma unroll
        for (int nf = 0; nf < 4; ++nf)
            bv[nf] = (MODE == 0) ? bias[nf * 256 + jcol] : bias[g0 + nf * 16 + lm];
    }

    #pragma unroll
    for (int mf = 0; mf < 2; ++mf) {
        #pragma unroll
        for (int r = 0; r < 4; ++r) {
            const int n = n0 + wv * 32 + mf * 16 + lg * 4 + r;
            if (MODE == 0) {
                ushort4 u;
                u.x = bfbits(acc[mf][0][r] + bv[0]);
                u.y = bfbits(acc[mf][1][r] + bv[1]);
                u.z = bfbits(acc[mf][2][r] + bv[2]);
                u.w = bfbits(acc[mf][3][r] + bv[3]);
                ((ushort4*)outp)[(long)n * 256 + jcol] = u;
            } else if (MODE == 1) {
                #pragma unroll
                for (int nf = 0; nf < 4; ++nf)
                    ((float*)outp)[(long)n * 512 + g0 + nf * 16 + lm] = acc[mf][nf][r] + bv[nf];
            } else {
                #pragma unroll
                for (int nf = 0; nf < 4; ++nf)
                    ((float*)outp)[(long)n * 4096 + g0 + nf * 16 + lm] = acc[mf][nf][r];
            }
        }
    }
}

// ---------------------------------------------------------------------------
// lstm_fp8: weight-stationary fp8 MFMA recurrence, 4 seqs/WG, 16 waves.
// Wave wv: hidden slice [16wv,16wv+16), all 4 gates in regs (wfrag, 64 VGPR).
// h double-buffered fp8 in LDS (rotated rows, conflict-free b64 reads).
// G interleaved: ushort4 {i,f,g,o} per (row, j). Out bf16, swapped-on-write:
// row_out = b*4096 + t*64 + (seq&63).
// ---------------------------------------------------------------------------
__global__ __launch_bounds__(1024, 4)
void lstm_fp8(const bf16* __restrict__ Gf, const bf16* __restrict__ Gb,
              const unsigned char* __restrict__ Wqf, const unsigned char* __restrict__ Wqb,
              bf16* __restrict__ Out, int dir_force)
{
    __shared__ unsigned char hbuf[2][4][256];     // fp8 h, rotated
    __shared__ float bnc[16][4][16][4];           // [wv][q][hid lm][seq r]
    const int tid = threadIdx.x;
    const int wv = tid >> 6, l = tid & 63;
    const int lm = l & 15, lg = l >> 4;
    const int j_c = wv * 16 + lm;                 // this lane's cell: unit j_c, seq lg

    int dir, sblk;
    if (dir_force >= 0) { dir = dir_force; sblk = blockIdx.x; }
    else               { dir = blockIdx.x >> 7; sblk = blockIdx.x & 127; }
    const bf16* G = dir ? Gb : Gf;
    const unsigned char* WQ = dir ? Wqb : Wqf;
    const int s0 = sblk << 2;

    // Whh fp8 B-fragments: col g = q*256 + j_c(lm part), k = kt*32 + lg*8 + j
    unsigned long wfrag[4][8];
    #pragma unroll
    for (int q = 0; q < 4; ++q) {
        const unsigned char* wr = WQ + (long)(q * 256 + wv * 16 + lm) * 256 + lg * 8;
        #pragma unroll
        for (int kt = 0; kt < 8; ++kt)
            wfrag[q][kt] = *(const unsigned long*)(wr + kt * 32);
    }

    ((short*)hbuf)[tid] = 0;      // zero both fp8 h buffers (2048 B)

    float c = 0.f;
    const ushort4* G4 = (const ushort4*)G;
    const long grow0 = (long)(s0 + lg) * 64;      // per-lane seq row base
    const int sg = s0 + lg;
    const long obase = ((long)((sg >> 6) * 4096 + (sg & 63))) * 512 + (dir << 8) + j_c;
    unsigned short* Ou = (unsigned short*)Out;

    ushort4 uA, uB;
    {
        int t0 = dir ? 63 : 0, t1 = dir ? 62 : 1;
        uA = G4[(grow0 + t0) * 256 + j_c];
        uB = G4[(grow0 + t1) * 256 + j_c];
    }
    __syncthreads();

#define LSTM_STEP(SP, UREG, RB, WB)                                             \
    {                                                                           \
        const int t_ = dir ? (63 - (SP)) : (SP);                                \
        unsigned long af[8];                                                    \
        {                                                                       \
            const unsigned char* hb = &hbuf[RB][0][0];                          \
            const int row = lm & 3;                                             \
            const int rbb = row * 256;                                          \
            _Pragma("unroll")                                                   \
            for (int kt = 0; kt < 8; ++kt)                                      \
                af[kt] = *(const unsigned long*)(hb + rbb +                     \
                          ((lg * 8 + kt * 32 + row * 32) & 255));               \
        }                                                                       \
        f4 ac0 = {0.f,0.f,0.f,0.f}, ac1 = {0.f,0.f,0.f,0.f};                    \
        f4 ac2 = {0.f,0.f,0.f,0.f}, ac3 = {0.f,0.f,0.f,0.f};                    \
        _Pragma("unroll")                                                       \
        for (int kt = 0; kt < 8; ++kt) {                                        \
            ac0 = __builtin_amdgcn_mfma_f32_16x16x32_fp8_fp8((long)af[kt], (long)wfrag[0][kt], ac0, 0, 0, 0); \
            ac1 = __builtin_amdgcn_mfma_f32_16x16x32_fp8_fp8((long)af[kt], (long)wfrag[1][kt], ac1, 0, 0, 0); \
            ac2 = __builtin_amdgcn_mfma_f32_16x16x32_fp8_fp8((long)af[kt], (long)wfrag[2][kt], ac2, 0, 0, 0); \
            ac3 = __builtin_amdgcn_mfma_f32_16x16x32_fp8_fp8((long)af[kt], (long)wfrag[3][kt], ac3, 0, 0, 0); \
        }                                                                       \
        if (lg == 0) {                                                          \
            *(f4*)&bnc[wv][0][lm][0] = ac0;                                     \
            *(f4*)&bnc[wv][1][lm][0] = ac1;                                     \
            *(f4*)&bnc[wv][2][lm][0] = ac2;                                     \
            *(f4*)&bnc[wv][3][lm][0] = ac3;                                     \
        }                                                                       \
        float gi = bnc[wv][0][lm][lg] + bf2f(UREG.x);                           \
        float gf = bnc[wv][1][lm][lg] + bf2f(UREG.y);                           \
        float gg = bnc[wv][2][lm][lg] + bf2f(UREG.z);                           \
        float go = bnc[wv][3][lm][lg] + bf2f(UREG.w);                           \
        float ii = sigm(gi), ff = sigm(gf), gc = tanh_fast(gg), oo = sigm(go);  \
        c = ff * c + ii * gc;                                                   \
        float h_ = oo * tanh_fast(c);                                           \
        {                                                                       \
            int sp2 = (SP) + 2; if (sp2 > 63) sp2 = 63;                         \
            int tp = dir ? (63 - sp2) : sp2;                                    \
            UREG = G4[(grow0 + tp) * 256 + j_c];                                \
        }                                                                       \
        hbuf[WB][lg][(j_c + lg * 32) & 255] = f2fp8(h_);                        \
        Ou[obase + (long)t_ * 32768] = bfbits(h_);                              \
        __syncthreads();                                                        \
    }

    for (int sp = 0; sp < 64; sp += 2) {
        LSTM_STEP(sp,     uA, 0, 1)
        LSTM_STEP(sp + 1, uB, 1, 0)
    }
#undef LSTM_STEP
}

// ---------------------------------------------------------------------------
// softmax_rows: convout fp32 [32768][512] -> kernT bf16 [32768][512].
// One wave per row; softmax over cols 0..483, cols 484..511 -> 0.
// ---------------------------------------------------------------------------
__global__ __launch_bounds__(256)
void softmax_rows(const float* __restrict__ cin, bf16* __restrict__ kout)
{
    const int tid = threadIdx.x;
    const int row = blockIdx.x * 4 + (tid >> 6);
    const int l = tid & 63;
    const float* rp = cin + (long)row * 512 + l * 8;
    float v[8];
    *(float4*)&v[0] = *(const float4*)rp;
    *(float4*)&v[4] = *(const float4*)(rp + 4);
    float m = -3.4e38f;
    #pragma unroll
    for (int i = 0; i < 8; ++i) {
        int o = l * 8 + i;
        if (o < 484) m = fmaxf(m, v[i]);
    }
    #pragma unroll
    for (int d = 1; d < 64; d <<= 1) m = fmaxf(m, __shfl_xor(m, d));
    float e[8], s = 0.f;
    #pragma unroll
    for (int i = 0; i < 8; ++i) {
        int o = l * 8 + i;
        e[i] = (o < 484) ? __expf(v[i] - m) : 0.f;
        s += e[i];
    }
    #pragma unroll
    for (int d = 1; d < 64; d <<= 1) s += __shfl_xor(s, d);
    float inv = 1.f / s;
    short8 st;
    #pragma unroll
    for (int i = 0; i < 8; ++i) st[i] = (short)bfbits(e[i] * inv);
    *(short8*)(kout + (long)row * 512 + l * 8) = st;
}

// ---------------------------------------------------------------------------
// gather_patch: Pch[b*512+c][o] = bf16(x[b, c, 3*(o/22), 3*(o%22)]), 0 o>=484.
// ---------------------------------------------------------------------------
__global__ __launch_bounds__(256)
void gather_patch(const float* __restrict__ x, bf16* __restrict__ Pch)
{
    int idx = blockIdx.x * 256 + threadIdx.x;
    if (idx >= 2097152) return;
    int o = idx & 511, c = (idx >> 9) & 511, b = idx >> 18;
    float v = 0.f;
    if (o < 484) {
        int i = o / 22, jj = o - i * 22;
        v = x[(long)b * 2097152 + (long)c * 4096 + i * 192 + jj * 3];
    }
    Pch[idx] = __float2bfloat16(v);
}

// ---------------------------------------------------------------------------
extern "C" void kernel_launch(void* const* d_in, const int* in_sizes, int n_in,
                              void* d_out, int out_size, void* d_ws, size_t ws_size,
                              hipStream_t stream)
{
    const float* x        = (const float*)d_in[0];
    const float* v_wih_f  = (const float*)d_in[1];
    const float* v_whh_f  = (const float*)d_in[2];
    const float* v_b_f    = (const float*)d_in[3];
    const float* v_wih_b  = (const float*)d_in[4];
    const float* v_whh_b  = (const float*)d_in[5];
    const float* v_b_b    = (const float*)d_in[6];
    const float* h_wih_f  = (const float*)d_in[7];
    const float* h_whh_f  = (const float*)d_in[8];
    const float* h_b_f    = (const float*)d_in[9];
    const float* h_wih_b  = (const float*)d_in[10];
    const float* h_whh_b  = (const float*)d_in[11];
    const float* h_b_b    = (const float*)d_in[12];
    const float* conv_w   = (const float*)d_in[13];
    const float* conv_b   = (const float*)d_in[14];

    const size_t REQ_FUSED  = 50331648UL * 4UL;   // 201,326,592 B
    const size_t REQ_SERIAL = 33554432UL * 4UL;   // 134,217,728 B
    if (ws_size < REQ_SERIAL) return;
    const bool fused = (ws_size >= REQ_FUSED);

    float* wsf = (float*)d_ws;
    float* out = (float*)d_out;

    // d_out tail scratch (dead before final_gemm)
    bf16*          wt   = (bf16*)(out + 8388608);
    bf16*          cw2b = (bf16*)(out + 9437184);
    float*         cb2  = out + 9568256;
    unsigned char* wq   = (unsigned char*)(out + 9568768);

    prep_weights<<<13314, 256, 0, stream>>>(v_wih_f, v_wih_b, h_wih_f, h_wih_b,
                                            conv_w, conv_b,
                                            v_whh_f, v_whh_b, h_whh_f, h_whh_b,
                                            wt, cw2b, cb2, wq);
    bf16* wt_vf = wt;
    bf16* wt_vb = wt + 524288;
    bf16* wt_hf = wt + 1048576;
    bf16* wt_hb = wt + 1572864;
    unsigned char* wq_vf = wq;
    unsigned char* wq_vb = wq + 262144;
    unsigned char* wq_hf = wq + 524288;
    unsigned char* wq_hb = wq + 786432;

    dim3 gG(16, 256);   // gate GEMMs: 1024 cols (16 j-tiles), 32768 rows
    dim3 gC(8, 256);    // conv: 512 cols, 32768 rows
    dim3 gF(64, 32);    // final: 4096 cols, 4096 rows

    if (fused) {
        bf16*  Gf    = (bf16*)d_ws;
        bf16*  Gb    = (bf16*)(wsf + 16777216);
        bf16*  V     = (bf16*)(wsf + 33554432);
        bf16*  HF    = (bf16*)(wsf + 41943040);
        bf16*  xt    = V;                      // dead after vertical GEMMs
        float* convo = (float*)d_ws;           // aliases Gf
        bf16*  kernT = Gb;                     // aliases Gb
        bf16*  Pch   = V;                      // aliases V

        xtrans<<<4096, 256, 0, stream>>>(x, xt);
        gemm_mfma<0><<<gG, 256, 0, stream>>>(xt, wt_vf, v_b_f, Gf);
        gemm_mfma<0><<<gG, 256, 0, stream>>>(xt, wt_vb, v_b_b, Gb);
        lstm_fp8<<<256, 1024, 0, stream>>>(Gf, Gb, wq_vf, wq_vb, V, -1);

        gemm_mfma<0><<<gG, 256, 0, stream>>>(V, wt_hf, h_b_f, Gf);
        gemm_mfma<0><<<gG, 256, 0, stream>>>(V, wt_hb, h_b_b, Gb);
        lstm_fp8<<<256, 1024, 0, stream>>>(Gf, Gb, wq_hf, wq_hb, HF, -1);

        gemm_mfma<1><<<gC, 256, 0, stream>>>(HF, cw2b, cb2, convo);
        softmax_rows<<<8192, 256, 0, stream>>>(convo, kernT);
        gather_patch<<<8192, 256, 0, stream>>>(x, Pch);
        gemm_mfma<2><<<gF, 256, 0, stream>>>(Pch, kernT, nullptr, out);
    } else {
        bf16*  G     = (bf16*)d_ws;
        bf16*  V     = (bf16*)(wsf + 16777216);
        bf16*  xt    = (bf16*)(wsf + 25165824);
        bf16*  HF    = xt;
        float* convo = (float*)d_ws;           // aliases G
        bf16*  kernT = V;
        bf16*  Pch   = (bf16*)d_ws;            // aliases convo after softmax

        xtrans<<<4096, 256, 0, stream>>>(x, xt);
        gemm_mfma<0><<<gG, 256, 0, stream>>>(xt, wt_vf, v_b_f, G);
        lstm_fp8<<<128, 1024, 0, stream>>>(G, G, wq_vf, wq_vf, V, 0);
        gemm_mfma<0><<<gG, 256, 0, stream>>>(xt, wt_vb, v_b_b, G);
        lstm_fp8<<<128, 1024, 0, stream>>>(G, G, wq_vb, wq_vb, V, 1);

        gemm_mfma<0><<<gG, 256, 0, stream>>>(V, wt_hf, h_b_f, G);
        lstm_fp8<<<128, 1024, 0, stream>>>(G, G, wq_hf, wq_hf, HF, 0);
        gemm_mfma<0><<<gG, 256, 0, stream>>>(V, wt_hb, h_b_b, G);
        lstm_fp8<<<128, 1024, 0, stream>>>(G, G, wq_hb, wq_hb, HF, 1);

        gemm_mfma<1><<<gC, 256, 0, stream>>>(HF, cw2b, cb2, convo);
        softmax_rows<<<8192, 256, 0, stream>>>(convo, kernT);
        gather_patch<<<8192, 256, 0, stream>>>(x, Pch);
        gemm_mfma<2><<<gF, 256, 0, stream>>>(Pch, kernT, nullptr, out);
    }
}

// Round 6
// 536.889 us; speedup vs baseline: 11.0199x; 2.1239x over previous
//
#include <hip/hip_runtime.h>
#include <hip/hip_bf16.h>
#include <hip/hip_fp8.h>
#include <math.h>

// ---------------------------------------------------------------------------
// PicanetG: Renet (2x BiLSTM, HID=256) + 1x1 conv(484) + softmax + attention.
// Round 5: m97-structure LDS-staged MFMA GEMM (global_load_lds width=16,
//   128x128 tile, BK=64, XOR-swizzled LDS both-sides) + fused fwd/bwd gate
//   GEMMs + XCD-chunked block swizzle. lstm_fp8 recurrence unchanged (R4).
//
// FUSED ws (float units), REQ = 50331648 fl = 201,326,592 B:
//   Gf @ 0         bf16 [32768 n][256 j] ushort4 (64 MiB); later convout fp32
//   Gb @ 16777216  bf16 (64 MiB); later kernT bf16 [8][4096][512] (32 MiB)
//   V  @ 33554432  bf16 [32768][512] (32 MiB); first xt, later Pch
//   HF @ 41943040  bf16 [32768][512] (32 MiB)
// SERIAL ws, REQ = 134,217,728 B: G@0, V@16777216, xt/HF@25165824.
// d_out tail scratch (fl offset): wt bf16 @ +8388608 ([vf;vb;hf;hb][512k]),
//   cw2b @ +9437184, cb2 @ +9568256, wq fp8 @ +9568768.
// ---------------------------------------------------------------------------

typedef __hip_bfloat16 bf16;
typedef short short8 __attribute__((ext_vector_type(8)));
typedef float f4 __attribute__((ext_vector_type(4)));

__device__ __forceinline__ unsigned short bfbits(float f) {
    bf16 h = __float2bfloat16(f);
    return *reinterpret_cast<unsigned short*>(&h);
}
__device__ __forceinline__ float bf2f(unsigned short u) {
    union { unsigned int i; float f; } x; x.i = ((unsigned int)u) << 16; return x.f;
}
__device__ __forceinline__ unsigned char f2fp8(float f) {
    __hip_fp8_e4m3 q(f);
    return *reinterpret_cast<unsigned char*>(&q);
}
__device__ __forceinline__ float sigm(float x) {
    return 1.0f / (1.0f + __expf(-x));
}
__device__ __forceinline__ float tanh_fast(float x) {
    float x2 = fminf(fmaxf(2.0f * x, -30.0f), 30.0f);
    float e = __expf(x2);
    return (e - 1.0f) / (e + 1.0f);
}

// async global->LDS, 16B per lane; lds dest = base + lane*16 (HW rule).
#define GLD16(g, s) __builtin_amdgcn_global_load_lds(                          \
    (const __attribute__((address_space(1))) void*)(g),                        \
    (__attribute__((address_space(3))) void*)(s), 16, 0, 0)

// ---------------------------------------------------------------------------
// prep_weights: wt bf16 [4][1024 g][512 k] ([vf;vb;hf;hb]); cw2b [512][512];
//               cb2 [512]; wq e4m3 [4][1024 g][256 k].
// ---------------------------------------------------------------------------
__global__ __launch_bounds__(256)
void prep_weights(const float* __restrict__ w0, const float* __restrict__ w1,
                  const float* __restrict__ w2, const float* __restrict__ w3,
                  const float* __restrict__ cw, const float* __restrict__ cb,
                  const float* __restrict__ u0, const float* __restrict__ u1,
                  const float* __restrict__ u2, const float* __restrict__ u3,
                  bf16* __restrict__ wt, bf16* __restrict__ cw2b,
                  float* __restrict__ cb2, unsigned char* __restrict__ wq)
{
    int idx = blockIdx.x * 256 + threadIdx.x;
    if (idx < 2097152) {
        int mat = idx >> 19, rem = idx & 524287;
        const float* src = (mat == 0) ? w0 : (mat == 1) ? w1 : (mat == 2) ? w2 : w3;
        wt[idx] = __float2bfloat16(src[rem]);
    } else if (idx < 2097152 + 262144) {
        int r = idx - 2097152; int o = r >> 9, k = r & 511;
        cw2b[r] = __float2bfloat16((o < 484) ? cw[o * 512 + k] : 0.f);
    } else if (idx < 2097152 + 262144 + 512) {
        int o = idx - 2097152 - 262144;
        cb2[o] = (o < 484) ? cb[o] : 0.f;
    } else if (idx < 2097152 + 262144 + 512 + 1048576) {
        int r = idx - 2097152 - 262144 - 512;
        int mat = r >> 18, rem = r & 262143;
        const float* src = (mat == 0) ? u0 : (mat == 1) ? u1 : (mat == 2) ? u2 : u3;
        wq[r] = f2fp8(src[rem]);
    }
}

// ---------------------------------------------------------------------------
// xtrans: x [8][512][64][64] fp32 -> xt [b*4096 + h*64 + w][512 c] bf16.
// ---------------------------------------------------------------------------
__global__ __launch_bounds__(256)
void xtrans(const float* __restrict__ x, bf16* __restrict__ xt)
{
    __shared__ float T[64][65];
    const int tid = threadIdx.x;
    const int bid = blockIdx.x;
    const int b = bid >> 9, h = (bid >> 3) & 63, ct = bid & 7;
    const int c0 = ct << 6;
    const float* xp = x + ((long)(b * 512 + c0) * 64 + h) * 64;
    const int wv = tid >> 6, wl = tid & 63;
    #pragma unroll
    for (int r = 0; r < 16; ++r) {
        int ci = wv + (r << 2);
        T[ci][wl] = xp[(long)ci * 4096 + wl];
    }
    __syncthreads();
    const int wr = tid >> 2, cj = (tid & 3) << 4;
    bf16* op = xt + ((long)(b * 4096 + h * 64 + wr) * 512) + c0 + cj;
    short8 v0, v1;
    #pragma unroll
    for (int i = 0; i < 8; ++i) v0[i] = (short)bfbits(T[cj + i][wr]);
    #pragma unroll
    for (int i = 0; i < 8; ++i) v1[i] = (short)bfbits(T[cj + 8 + i][wr]);
    *(short8*)op = v0;
    *(short8*)(op + 8) = v1;
}

// ---------------------------------------------------------------------------
// gemm_lds: m97-structure MFMA GEMM. K=512, BK=64, tile 128x128, 256 thr.
// A [M][512] bf16 rows k-contiguous. LDS As/Bs [128 rows][64 k] bf16,
// XOR-swizzled byte^=((row&7)<<4) on BOTH stage-source and ds_read (rule 21).
// Waves 2x2: wm=wv>>1 (M64), wn=wv&1. Frag maps (HW-verified R4/R5):
//   A row=lm, k=lg*8+j; B col=lm, same k; D row=lg*4+r, col=lm.
// MODE 0 GATES: fused fwd+bwd. bx: dir=bx>>3 (or dironly), jblk. Block cols =
//   4 gates x 32 j. B LDS row bw = nf*32+wn*16+lm -> W row dir*1024+nf*256+
//   jblk*32+(bw&31). Out: interleaved ushort4 {i,f,g,o} at Gdir[n*256+j].
// MODE 1 CONV : N=512, out fp32 [n][512]+bias.
// MODE 2 FINAL: N=4096 per b (W=kernT+b*2M), out fp32 [n][4096], no bias.
// XCD-chunked bid swizzle (nwg % 8 == 0 in all grids).
// ---------------------------------------------------------------------------
template<int MODE>
__global__ __launch_bounds__(256)
void gemm_lds(const bf16* __restrict__ A, const bf16* __restrict__ W,
              const float* __restrict__ biasf, const float* __restrict__ biasb,
              void* __restrict__ outf, void* __restrict__ outb, int dironly)
{
    __shared__ alignas(16) char Abuf[16384];
    __shared__ alignas(16) char Bbuf[16384];
    const int tid = threadIdx.x;
    const int wv = tid >> 6, l = tid & 63;
    const int lm = l & 15, lg = l >> 4;
    const int wm = wv >> 1, wn = wv & 1;

    const int nx = gridDim.x;
    int bid = blockIdx.y * nx + blockIdx.x;
    const int cpx = (nx * gridDim.y) >> 3;
    bid = (bid & 7) * cpx + (bid >> 3);
    const int bx = bid % nx;
    const int n0 = (bid / nx) << 7;

    int dir = 0, jblk = 0, g0 = 0;
    const bf16* Wg = W;
    if (MODE == 0) {
        dir  = (dironly < 0) ? (bx >> 3) : dironly;
        jblk = (dironly < 0) ? (bx & 7) : bx;
    } else {
        g0 = bx << 7;
        if (MODE == 2) Wg += (long)(n0 >> 9) * 2097152;
    }

    f4 acc[4][4];
    #pragma unroll
    for (int mf = 0; mf < 4; ++mf)
        #pragma unroll
        for (int nf = 0; nf < 4; ++nf)
            acc[mf][nf] = (f4){0.f, 0.f, 0.f, 0.f};

    for (int kt = 0; kt < 8; ++kt) {
        const int k0 = kt << 6;
        // ---- stage A tile (16 KB) ----
        #pragma unroll
        for (int i = 0; i < 4; ++i) {
            const int seg = (wv << 2) + i;
            const int L = (seg << 10) + l * 16;
            const int row = L >> 7;
            const int off = (L & 127) ^ ((row & 7) << 4);   // inverse swizzle
            const bf16* ga = A + (long)(n0 + row) * 512 + k0 + (off >> 1);
            GLD16(ga, &Abuf[seg << 10]);
        }
        // ---- stage B tile (16 KB) ----
        #pragma unroll
        for (int i = 0; i < 4; ++i) {
            const int seg = (wv << 2) + i;
            const int L = (seg << 10) + l * 16;
            const int row = L >> 7;
            const int off = (L & 127) ^ ((row & 7) << 4);
            int wrow;
            if (MODE == 0) wrow = (dir << 10) + ((row >> 5) << 8) + jblk * 32 + (row & 31);
            else           wrow = g0 + row;
            const bf16* gb = Wg + (long)wrow * 512 + k0 + (off >> 1);
            GLD16(gb, &Bbuf[seg << 10]);
        }
        __syncthreads();   // drains vmcnt(0), tile visible

        #pragma unroll
        for (int kk = 0; kk < 2; ++kk) {
            short8 af[4], bq[4];
            #pragma unroll
            for (int mf = 0; mf < 4; ++mf) {
                const int row = wm * 64 + mf * 16 + lm;
                const int ad = (row << 7) + ((((kk << 6) + (lg << 4))) ^ ((row & 7) << 4));
                af[mf] = *(const short8*)&Abuf[ad];
            }
            #pragma unroll
            for (int nf = 0; nf < 4; ++nf) {
                const int row = (MODE == 0) ? (nf * 32 + wn * 16 + lm)
                                            : (wn * 64 + nf * 16 + lm);
                const int ad = (row << 7) + ((((kk << 6) + (lg << 4))) ^ ((row & 7) << 4));
                bq[nf] = *(const short8*)&Bbuf[ad];
            }
            #pragma unroll
            for (int mf = 0; mf < 4; ++mf)
                #pragma unroll
                for (int nf = 0; nf < 4; ++nf)
                    acc[mf][nf] = __builtin_amdgcn_mfma_f32_16x16x32_bf16(af[mf], bq[nf], acc[mf][nf], 0, 0, 0);
        }
        __syncthreads();   // protect tile before next overwrite
    }

    if (MODE == 0) {
        const float* bs = dir ? biasb : biasf;
        const int jglob = jblk * 32 + wn * 16 + lm;
        float bv[4];
        #pragma unroll
        for (int nf = 0; nf < 4; ++nf) bv[nf] = bs[nf * 256 + jglob];
        ushort4* Gd = (ushort4*)(dir ? outb : outf);
        #pragma unroll
        for (int mf = 0; mf < 4; ++mf) {
            #pragma unroll
            for (int r = 0; r < 4; ++r) {
                const int n = n0 + wm * 64 + mf * 16 + lg * 4 + r;
                ushort4 u;
                u.x = bfbits(acc[mf][0][r] + bv[0]);
                u.y = bfbits(acc[mf][1][r] + bv[1]);
                u.z = bfbits(acc[mf][2][r] + bv[2]);
                u.w = bfbits(acc[mf][3][r] + bv[3]);
                Gd[(long)n * 256 + jglob] = u;
            }
        }
    } else if (MODE == 1) {
        float bv[4];
        #pragma unroll
        for (int nf = 0; nf < 4; ++nf) bv[nf] = biasf[g0 + wn * 64 + nf * 16 + lm];
        float* o = (float*)outf;
        #pragma unroll
        for (int mf = 0; mf < 4; ++mf)
            #pragma unroll
            for (int r = 0; r < 4; ++r) {
                const int n = n0 + wm * 64 + mf * 16 + lg * 4 + r;
                #pragma unroll
                for (int nf = 0; nf < 4; ++nf)
                    o[(long)n * 512 + g0 + wn * 64 + nf * 16 + lm] = acc[mf][nf][r] + bv[nf];
            }
    } else {
        float* o = (float*)outf;
        #pragma unroll
        for (int mf = 0; mf < 4; ++mf)
            #pragma unroll
            for (int r = 0; r < 4; ++r) {
                const int n = n0 + wm * 64 + mf * 16 + lg * 4 + r;
                #pragma unroll
                for (int nf = 0; nf < 4; ++nf)
                    o[(long)n * 4096 + g0 + wn * 64 + nf * 16 + lm] = acc[mf][nf][r];
            }
    }
}

// ---------------------------------------------------------------------------
// lstm_fp8: weight-stationary fp8 MFMA recurrence, 4 seqs/WG, 16 waves (R4).
// ---------------------------------------------------------------------------
__global__ __launch_bounds__(1024, 4)
void lstm_fp8(const bf16* __restrict__ Gf, const bf16* __restrict__ Gb,
              const unsigned char* __restrict__ Wqf, const unsigned char* __restrict__ Wqb,
              bf16* __restrict__ Out, int dir_force)
{
    __shared__ unsigned char hbuf[2][4][256];     // fp8 h, rotated
    __shared__ float bnc[16][4][16][4];           // [wv][q][hid lm][seq r]
    const int tid = threadIdx.x;
    const int wv = tid >> 6, l = tid & 63;
    const int lm = l & 15, lg = l >> 4;
    const int j_c = wv * 16 + lm;

    int dir, sblk;
    if (dir_force >= 0) { dir = dir_force; sblk = blockIdx.x; }
    else               { dir = blockIdx.x >> 7; sblk = blockIdx.x & 127; }
    const bf16* G = dir ? Gb : Gf;
    const unsigned char* WQ = dir ? Wqb : Wqf;
    const int s0 = sblk << 2;

    unsigned long wfrag[4][8];
    #pragma unroll
    for (int q = 0; q < 4; ++q) {
        const unsigned char* wr = WQ + (long)(q * 256 + wv * 16 + lm) * 256 + lg * 8;
        #pragma unroll
        for (int kt = 0; kt < 8; ++kt)
            wfrag[q][kt] = *(const unsigned long*)(wr + kt * 32);
    }

    ((short*)hbuf)[tid] = 0;

    float c = 0.f;
    const ushort4* G4 = (const ushort4*)G;
    const long grow0 = (long)(s0 + lg) * 64;
    const int sg = s0 + lg;
    const long obase = ((long)((sg >> 6) * 4096 + (sg & 63))) * 512 + (dir << 8) + j_c;
    unsigned short* Ou = (unsigned short*)Out;

    ushort4 uA, uB;
    {
        int t0 = dir ? 63 : 0, t1 = dir ? 62 : 1;
        uA = G4[(grow0 + t0) * 256 + j_c];
        uB = G4[(grow0 + t1) * 256 + j_c];
    }
    __syncthreads();

#define LSTM_STEP(SP, UREG, RB, WB)                                             \
    {                                                                           \
        const int t_ = dir ? (63 - (SP)) : (SP);                                \
        unsigned long af[8];                                                    \
        {                                                                       \
            const unsigned char* hb = &hbuf[RB][0][0];                          \
            const int row = lm & 3;                                             \
            const int rbb = row * 256;                                          \
            _Pragma("unroll")                                                   \
            for (int kt = 0; kt < 8; ++kt)                                      \
                af[kt] = *(const unsigned long*)(hb + rbb +                     \
                          ((lg * 8 + kt * 32 + row * 32) & 255));               \
        }                                                                       \
        f4 ac0 = {0.f,0.f,0.f,0.f}, ac1 = {0.f,0.f,0.f,0.f};                    \
        f4 ac2 = {0.f,0.f,0.f,0.f}, ac3 = {0.f,0.f,0.f,0.f};                    \
        _Pragma("unroll")                                                       \
        for (int kt = 0; kt < 8; ++kt) {                                        \
            ac0 = __builtin_amdgcn_mfma_f32_16x16x32_fp8_fp8((long)af[kt], (long)wfrag[0][kt], ac0, 0, 0, 0); \
            ac1 = __builtin_amdgcn_mfma_f32_16x16x32_fp8_fp8((long)af[kt], (long)wfrag[1][kt], ac1, 0, 0, 0); \
            ac2 = __builtin_amdgcn_mfma_f32_16x16x32_fp8_fp8((long)af[kt], (long)wfrag[2][kt], ac2, 0, 0, 0); \
            ac3 = __builtin_amdgcn_mfma_f32_16x16x32_fp8_fp8((long)af[kt], (long)wfrag[3][kt], ac3, 0, 0, 0); \
        }                                                                       \
        if (lg == 0) {                                                          \
            *(f4*)&bnc[wv][0][lm][0] = ac0;                                     \
            *(f4*)&bnc[wv][1][lm][0] = ac1;                                     \
            *(f4*)&bnc[wv][2][lm][0] = ac2;                                     \
            *(f4*)&bnc[wv][3][lm][0] = ac3;                                     \
        }                                                                       \
        float gi = bnc[wv][0][lm][lg] + bf2f(UREG.x);                           \
        float gf = bnc[wv][1][lm][lg] + bf2f(UREG.y);                           \
        float gg = bnc[wv][2][lm][lg] + bf2f(UREG.z);                           \
        float go = bnc[wv][3][lm][lg] + bf2f(UREG.w);                           \
        float ii = sigm(gi), ff = sigm(gf), gc = tanh_fast(gg), oo = sigm(go);  \
        c = ff * c + ii * gc;                                                   \
        float h_ = oo * tanh_fast(c);                                           \
        {                                                                       \
            int sp2 = (SP) + 2; if (sp2 > 63) sp2 = 63;                         \
            int tp = dir ? (63 - sp2) : sp2;                                    \
            UREG = G4[(grow0 + tp) * 256 + j_c];                                \
        }                                                                       \
        hbuf[WB][lg][(j_c + lg * 32) & 255] = f2fp8(h_);                        \
        Ou[obase + (long)t_ * 32768] = bfbits(h_);                              \
        __syncthreads();                                                        \
    }

    for (int sp = 0; sp < 64; sp += 2) {
        LSTM_STEP(sp,     uA, 0, 1)
        LSTM_STEP(sp + 1, uB, 1, 0)
    }
#undef LSTM_STEP
}

// ---------------------------------------------------------------------------
// softmax_rows: convout fp32 [32768][512] -> kernT bf16 [32768][512].
// ---------------------------------------------------------------------------
__global__ __launch_bounds__(256)
void softmax_rows(const float* __restrict__ cin, bf16* __restrict__ kout)
{
    const int tid = threadIdx.x;
    const int row = blockIdx.x * 4 + (tid >> 6);
    const int l = tid & 63;
    const float* rp = cin + (long)row * 512 + l * 8;
    float v[8];
    *(float4*)&v[0] = *(const float4*)rp;
    *(float4*)&v[4] = *(const float4*)(rp + 4);
    float m = -3.4e38f;
    #pragma unroll
    for (int i = 0; i < 8; ++i) {
        int o = l * 8 + i;
        if (o < 484) m = fmaxf(m, v[i]);
    }
    #pragma unroll
    for (int d = 1; d < 64; d <<= 1) m = fmaxf(m, __shfl_xor(m, d));
    float e[8], s = 0.f;
    #pragma unroll
    for (int i = 0; i < 8; ++i) {
        int o = l * 8 + i;
        e[i] = (o < 484) ? __expf(v[i] - m) : 0.f;
        s += e[i];
    }
    #pragma unroll
    for (int d = 1; d < 64; d <<= 1) s += __shfl_xor(s, d);
    float inv = 1.f / s;
    short8 st;
    #pragma unroll
    for (int i = 0; i < 8; ++i) st[i] = (short)bfbits(e[i] * inv);
    *(short8*)(kout + (long)row * 512 + l * 8) = st;
}

// ---------------------------------------------------------------------------
// gather_patch: Pch[b*512+c][o] = bf16(x[b, c, 3*(o/22), 3*(o%22)]), 0 o>=484.
// ---------------------------------------------------------------------------
__global__ __launch_bounds__(256)
void gather_patch(const float* __restrict__ x, bf16* __restrict__ Pch)
{
    int idx = blockIdx.x * 256 + threadIdx.x;
    if (idx >= 2097152) return;
    int o = idx & 511, c = (idx >> 9) & 511, b = idx >> 18;
    float v = 0.f;
    if (o < 484) {
        int i = o / 22, jj = o - i * 22;
        v = x[(long)b * 2097152 + (long)c * 4096 + i * 192 + jj * 3];
    }
    Pch[idx] = __float2bfloat16(v);
}

// ---------------------------------------------------------------------------
extern "C" void kernel_launch(void* const* d_in, const int* in_sizes, int n_in,
                              void* d_out, int out_size, void* d_ws, size_t ws_size,
                              hipStream_t stream)
{
    const float* x        = (const float*)d_in[0];
    const float* v_wih_f  = (const float*)d_in[1];
    const float* v_whh_f  = (const float*)d_in[2];
    const float* v_b_f    = (const float*)d_in[3];
    const float* v_wih_b  = (const float*)d_in[4];
    const float* v_whh_b  = (const float*)d_in[5];
    const float* v_b_b    = (const float*)d_in[6];
    const float* h_wih_f  = (const float*)d_in[7];
    const float* h_whh_f  = (const float*)d_in[8];
    const float* h_b_f    = (const float*)d_in[9];
    const float* h_wih_b  = (const float*)d_in[10];
    const float* h_whh_b  = (const float*)d_in[11];
    const float* h_b_b    = (const float*)d_in[12];
    const float* conv_w   = (const float*)d_in[13];
    const float* conv_b   = (const float*)d_in[14];

    const size_t REQ_FUSED  = 50331648UL * 4UL;   // 201,326,592 B
    const size_t REQ_SERIAL = 33554432UL * 4UL;   // 134,217,728 B
    if (ws_size < REQ_SERIAL) return;
    const bool fused = (ws_size >= REQ_FUSED);

    float* wsf = (float*)d_ws;
    float* out = (float*)d_out;

    // d_out tail scratch (dead before final gemm)
    bf16*          wt   = (bf16*)(out + 8388608);
    bf16*          cw2b = (bf16*)(out + 9437184);
    float*         cb2  = out + 9568256;
    unsigned char* wq   = (unsigned char*)(out + 9568768);

    prep_weights<<<13314, 256, 0, stream>>>(v_wih_f, v_wih_b, h_wih_f, h_wih_b,
                                            conv_w, conv_b,
                                            v_whh_f, v_whh_b, h_whh_f, h_whh_b,
                                            wt, cw2b, cb2, wq);
    bf16* wt_v = wt;                 // [vf;vb] 2048 rows
    bf16* wt_h = wt + 1048576;       // [hf;hb] 2048 rows
    unsigned char* wq_vf = wq;
    unsigned char* wq_vb = wq + 262144;
    unsigned char* wq_hf = wq + 524288;
    unsigned char* wq_hb = wq + 786432;

    dim3 gG(16, 256);   // fused gate GEMM: 2 dirs x 8 jblks, 256 row-tiles
    dim3 gGs(8, 256);   // serial gate GEMM: one dir
    dim3 gC(4, 256);    // conv: 512 cols
    dim3 gF(32, 32);    // final: 4096 cols, 4096 rows

    if (fused) {
        bf16*  Gf    = (bf16*)d_ws;
        bf16*  Gb    = (bf16*)(wsf + 16777216);
        bf16*  V     = (bf16*)(wsf + 33554432);
        bf16*  HF    = (bf16*)(wsf + 41943040);
        bf16*  xt    = V;                      // dead after vertical GEMM
        float* convo = (float*)d_ws;           // aliases Gf
        bf16*  kernT = Gb;                     // aliases Gb
        bf16*  Pch   = V;                      // aliases V

        xtrans<<<4096, 256, 0, stream>>>(x, xt);
        gemm_lds<0><<<gG, 256, 0, stream>>>(xt, wt_v, v_b_f, v_b_b, Gf, Gb, -1);
        lstm_fp8<<<256, 1024, 0, stream>>>(Gf, Gb, wq_vf, wq_vb, V, -1);

        gemm_lds<0><<<gG, 256, 0, stream>>>(V, wt_h, h_b_f, h_b_b, Gf, Gb, -1);
        lstm_fp8<<<256, 1024, 0, stream>>>(Gf, Gb, wq_hf, wq_hb, HF, -1);

        gemm_lds<1><<<gC, 256, 0, stream>>>(HF, cw2b, cb2, nullptr, convo, nullptr, 0);
        softmax_rows<<<8192, 256, 0, stream>>>(convo, kernT);
        gather_patch<<<8192, 256, 0, stream>>>(x, Pch);
        gemm_lds<2><<<gF, 256, 0, stream>>>(Pch, kernT, nullptr, nullptr, out, nullptr, 0);
    } else {
        bf16*  G     = (bf16*)d_ws;
        bf16*  V     = (bf16*)(wsf + 16777216);
        bf16*  xt    = (bf16*)(wsf + 25165824);
        bf16*  HF    = xt;
        float* convo = (float*)d_ws;           // aliases G
        bf16*  kernT = V;
        bf16*  Pch   = (bf16*)d_ws;            // aliases convo after softmax

        xtrans<<<4096, 256, 0, stream>>>(x, xt);
        gemm_lds<0><<<gGs, 256, 0, stream>>>(xt, wt_v, v_b_f, v_b_b, G, G, 0);
        lstm_fp8<<<128, 1024, 0, stream>>>(G, G, wq_vf, wq_vf, V, 0);
        gemm_lds<0><<<gGs, 256, 0, stream>>>(xt, wt_v, v_b_f, v_b_b, G, G, 1);
        lstm_fp8<<<128, 1024, 0, stream>>>(G, G, wq_vb, wq_vb, V, 1);

        gemm_lds<0><<<gGs, 256, 0, stream>>>(V, wt_h, h_b_f, h_b_b, G, G, 0);
        lstm_fp8<<<128, 1024, 0, stream>>>(G, G, wq_hf, wq_hf, HF, 0);
        gemm_lds<0><<<gGs, 256, 0, stream>>>(V, wt_h, h_b_f, h_b_b, G, G, 1);
        lstm_fp8<<<128, 1024, 0, stream>>>(G, G, wq_hb, wq_hb, HF, 1);

        gemm_lds<1><<<gC, 256, 0, stream>>>(HF, cw2b, cb2, nullptr, convo, nullptr, 0);
        softmax_rows<<<8192, 256, 0, stream>>>(convo, kernT);
        gather_patch<<<8192, 256, 0, stream>>>(x, Pch);
        gemm_lds<2><<<gF, 256, 0, stream>>>(Pch, kernT, nullptr, nullptr, out, nullptr, 0);
    }
}